// Round 12
// baseline (1834.101 us; speedup 1.0000x reference)
//
#include <hip/hip_runtime.h>
#include <hip/hip_bf16.h>

#define B_   32
#define N_   207
#define T_   12
#define D_   128
#define H_   8
#define HD_  16
#define L_   4
#define FF_  512
#define PL_  12
#define TOK  (B_*N_*T_)      // 79488 = 621*128
#define ROWS2 (B_*N_)        // 6624
#define SCALE_ 0.25f
#define LOG2E_ 1.4426950408889634f
#define NEG2_ -1.4426950409e9f   // -1e9 in log2 domain
#define KVH  232             // Vt/P row stride (fp16)
#define SLAB 3312            // 207*16 elements per (b,t,h) slab
#define MSK_N (13*13*256)    // mask elements in C-frag layout

typedef __hip_bfloat16 bf16;
typedef unsigned int u32;
typedef __attribute__((ext_vector_type(4))) unsigned int u32x4;
typedef __attribute__((ext_vector_type(8))) short bf16x8;     // 8 bf16 (MFMA A/B frag)
typedef __attribute__((ext_vector_type(8))) _Float16 f16x8;   // 8 fp16 (MFMA A/B frag)
typedef __attribute__((ext_vector_type(4))) float f32x4;      // MFMA C/D frag

__device__ __forceinline__ float b2f(bf16 x){ return __bfloat162float(x); }
__device__ __forceinline__ bf16  f2b(float x){ return __float2bfloat16(x); }

// async global->LDS 16B per lane (dest must be wave-uniform base + lane*16)
__device__ __forceinline__ void gll16(const bf16* g, bf16* l){
  __builtin_amdgcn_global_load_lds((const __attribute__((address_space(1))) void*)g,
                                   (__attribute__((address_space(3))) void*)l, 16, 0, 0);
}

// ---- dtype detection ----
__global__ void detect_k(const void* x, int* flag){
  __shared__ int cnt[256];
  const unsigned short* u = (const unsigned short*)x;
  int ok = 0;
  for (int i = threadIdx.x; i < 4096; i += 256){
    unsigned int bits = ((unsigned int)u[i]) << 16;
    float f = __uint_as_float(bits);
    float a = fabsf(f);
    if (f == 0.0f || (a > 1e-4f && a < 64.0f)) ok++;
  }
  cnt[threadIdx.x] = ok;
  __syncthreads();
  for (int s = 128; s > 0; s >>= 1){
    if (threadIdx.x < s) cnt[threadIdx.x] += cnt[threadIdx.x + s];
    __syncthreads();
  }
  if (threadIdx.x == 0) *flag = (cnt[0] > 3686) ? 1 : 0;
}

// ---- batched flat convert ----
struct FlatArgs {
  const void* src[24];
  long long dst[24];
  int cum[25];
};
__global__ void cvt_flat_k(FlatArgs a, bf16* base, const int* flag, int total){
  int i = blockIdx.x*256 + threadIdx.x;
  if (i >= total) return;
  int j = 0;
  while (i >= a.cum[j+1]) j++;
  int loc = i - a.cum[j];
  float v = (*flag) ? b2f(((const bf16*)a.src[j])[loc]) : ((const float*)a.src[j])[loc];
  base[a.dst[j] + loc] = f2b(v);
}

// ---- batched transpose convert (with per-segment scale) ----
struct TArgs {
  const void* src[10];
  long long dst[10];
  int K[10], Nc[10], Lstr[10], ro[10];
  float scale[10];
  int cum[11];
};
__global__ void cvt_t_k(TArgs a, bf16* base, const int* flag, int total){
  int i = blockIdx.x*256 + threadIdx.x;
  if (i >= total) return;
  int j = 0;
  while (i >= a.cum[j+1]) j++;
  int loc = i - a.cum[j];
  int KN = a.K[j]*a.Nc[j];
  int l = loc / KN; int rm = loc - l*KN; int k = rm / a.Nc[j]; int n = rm - k*a.Nc[j];
  float v = (*flag) ? b2f(((const bf16*)a.src[j])[loc]) : ((const float*)a.src[j])[loc];
  base[a.dst[j] + (long long)l*a.Lstr[j] + (long long)(a.ro[j]+n)*a.K[j] + k] = f2b(v*a.scale[j]);
}

// ---- additive mask in MFMA C-fragment layout (log2 domain) ----
__global__ void maskc_k(const int* adj, float* maskg){
  int i = blockIdx.x*256 + threadIdx.x;
  if (i >= MSK_N) return;
  int cell = i >> 8;             // mi*13+nj
  int mi = cell / 13, nj = cell - mi*13;
  int rem = i & 255;
  int lane = rem >> 2, r = rem & 3;
  int quad = lane >> 4, cl = lane & 15;
  int row = mi*16 + quad*4 + r; if (row > 206) row = 206;
  int col = nj*16 + cl;
  float v;
  if (col > 206) v = -1e30f;
  else v = adj[row*N_ + col] ? 0.0f : NEG2_;
  maskg[i] = v;
}

// ---- embed + fused LN (layer 0) ----
__global__ void embed_ln_k(const bf16* x, const bf16* Wi, const bf16* bi,
                           const bf16* g, const bf16* bta, float* h, bf16* xnb){
  int wave = threadIdx.x >> 6, lane = threadIdx.x & 63;
  int tok = blockIdx.x*4 + wave;
  if (tok >= TOK) return;
  float xv = b2f(x[tok]);
  float v0 = xv*b2f(Wi[lane])    + b2f(bi[lane]);
  float v1 = xv*b2f(Wi[lane+64]) + b2f(bi[lane+64]);
  float* hp = h + (size_t)tok*D_;
  hp[lane] = v0; hp[lane+64] = v1;
  float s = v0 + v1;
  for (int off = 32; off >= 1; off >>= 1) s += __shfl_xor(s, off, 64);
  float m = s * (1.0f/128.0f);
  float d0 = v0 - m, d1 = v1 - m;
  float vv = d0*d0 + d1*d1;
  for (int off = 32; off >= 1; off >>= 1) vv += __shfl_xor(vv, off, 64);
  float r = rsqrtf(vv*(1.0f/128.0f) + 1e-5f);
  bf16* op = xnb + (size_t)tok*D_;
  op[lane]    = f2b(d0*r*b2f(g[lane])    + b2f(bta[lane]));
  op[lane+64] = f2b(d1*r*b2f(g[lane+64]) + b2f(bta[lane+64]));
}

// ---- MFMA GEMM (non-acc), global_load_lds staging ----
__global__ __launch_bounds__(256) void mgemm_k(const bf16* __restrict__ A,
    const bf16* __restrict__ Wt, const bf16* __restrict__ bias,
    bf16* __restrict__ outp, int ldo, int Ktot, int relu){
  __shared__ __align__(16) bf16 As[128*32];
  __shared__ __align__(16) bf16 Bs[128*32];
  int tid = threadIdx.x;
  int rowBase = blockIdx.y * 128, colBase = blockIdx.x * 128;
  int w = tid >> 6, lane = tid & 63, quad = lane >> 4, cl = lane & 15;
  int waveM = w >> 1, waveN = w & 1;
  f32x4 accr[4][4];
  #pragma unroll
  for (int i = 0; i < 4; i++)
    #pragma unroll
    for (int j = 0; j < 4; j++) accr[i][j] = (f32x4){0.f,0.f,0.f,0.f};
  int lr = tid >> 2, kc = tid & 3;
  const bf16* Ap = A  + (size_t)(rowBase + lr)*Ktot + kc*8;
  const bf16* Bp = Wt + (size_t)(colBase + lr)*Ktot + kc*8;
  bf16* AsW = As + tid*8;
  bf16* BsW = Bs + tid*8;
  for (int kk = 0; kk < Ktot; kk += 32){
    __syncthreads();
    gll16(Ap + kk, AsW);
    gll16(Ap + (size_t)64*Ktot + kk, AsW + 64*32);
    gll16(Bp + kk, BsW);
    gll16(Bp + (size_t)64*Ktot + kk, BsW + 64*32);
    __syncthreads();
    bf16x8 af[4], bfr[4];
    #pragma unroll
    for (int mi = 0; mi < 4; mi++)
      af[mi] = *(const bf16x8*)(As + (waveM*64 + mi*16 + cl)*32 + quad*8);
    #pragma unroll
    for (int nj = 0; nj < 4; nj++)
      bfr[nj] = *(const bf16x8*)(Bs + (waveN*64 + nj*16 + cl)*32 + quad*8);
    #pragma unroll
    for (int mi = 0; mi < 4; mi++)
      #pragma unroll
      for (int nj = 0; nj < 4; nj++)
        accr[mi][nj] = __builtin_amdgcn_mfma_f32_16x16x32_bf16(af[mi], bfr[nj], accr[mi][nj], 0,0,0);
  }
  float bv[4];
  #pragma unroll
  for (int nj = 0; nj < 4; nj++)
    bv[nj] = bias ? b2f(bias[colBase + waveN*64 + nj*16 + cl]) : 0.0f;
  #pragma unroll
  for (int mi = 0; mi < 4; mi++){
    int row0 = rowBase + waveM*64 + mi*16 + quad*4;
    #pragma unroll
    for (int nj = 0; nj < 4; nj++){
      int col = colBase + waveN*64 + nj*16 + cl;
      #pragma unroll
      for (int r = 0; r < 4; r++){
        float v = accr[mi][nj][r] + bv[nj];
        if (relu) v = fmaxf(v, 0.0f);
        outp[(size_t)(row0+r)*ldo + col] = f2b(v);
      }
    }
  }
}

// ---- MFMA GEMM writing spatial q/k/v in [slab=(b,t,h)][n][16] layout ----
__global__ __launch_bounds__(256) void mgemm_qkvT_k(const bf16* __restrict__ A,
    const bf16* __restrict__ Wt, bf16* __restrict__ sQ,
    bf16* __restrict__ sK, bf16* __restrict__ sV){
  __shared__ __align__(16) bf16 As[128*32];
  __shared__ __align__(16) bf16 Bs[128*32];
  const int Ktot = 128;
  int tid = threadIdx.x;
  int rowBase = blockIdx.y * 128, colBase = blockIdx.x * 128;
  int w = tid >> 6, lane = tid & 63, quad = lane >> 4, cl = lane & 15;
  int waveM = w >> 1, waveN = w & 1;
  f32x4 accr[4][4];
  #pragma unroll
  for (int i = 0; i < 4; i++)
    #pragma unroll
    for (int j = 0; j < 4; j++) accr[i][j] = (f32x4){0.f,0.f,0.f,0.f};
  int lr = tid >> 2, kc = tid & 3;
  const bf16* Ap = A  + (size_t)(rowBase + lr)*Ktot + kc*8;
  const bf16* Bp = Wt + (size_t)(colBase + lr)*Ktot + kc*8;
  bf16* AsW = As + tid*8;
  bf16* BsW = Bs + tid*8;
  for (int kk = 0; kk < Ktot; kk += 32){
    __syncthreads();
    gll16(Ap + kk, AsW);
    gll16(Ap + (size_t)64*Ktot + kk, AsW + 64*32);
    gll16(Bp + kk, BsW);
    gll16(Bp + (size_t)64*Ktot + kk, BsW + 64*32);
    __syncthreads();
    bf16x8 af[4], bfr[4];
    #pragma unroll
    for (int mi = 0; mi < 4; mi++)
      af[mi] = *(const bf16x8*)(As + (waveM*64 + mi*16 + cl)*32 + quad*8);
    #pragma unroll
    for (int nj = 0; nj < 4; nj++)
      bfr[nj] = *(const bf16x8*)(Bs + (waveN*64 + nj*16 + cl)*32 + quad*8);
    #pragma unroll
    for (int mi = 0; mi < 4; mi++)
      #pragma unroll
      for (int nj = 0; nj < 4; nj++)
        accr[mi][nj] = __builtin_amdgcn_mfma_f32_16x16x32_bf16(af[mi], bfr[nj], accr[mi][nj], 0,0,0);
  }
  #pragma unroll
  for (int mi = 0; mi < 4; mi++){
    #pragma unroll
    for (int r = 0; r < 4; r++){
      int tok = rowBase + waveM*64 + mi*16 + quad*4 + r;
      int bn = tok / T_; int t = tok - bn*T_;
      int b = bn / N_;  int n = bn - b*N_;
      size_t base = ((size_t)(b*T_ + t)*H_)*SLAB + n*16 + cl;
      #pragma unroll
      for (int nj = 0; nj < 4; nj++){
        int col = colBase + waveN*64 + nj*16;
        int part = col >> 7, hh = (col >> 4) & 7;
        bf16* dst = (part == 0) ? sQ : (part == 1) ? sK : sV;
        dst[base + (size_t)hh*SLAB] = f2b(accr[mi][nj][r]);
      }
    }
  }
}

// ---- MFMA GEMM + residual-acc + fused LayerNorm (N=128, grid.x=1) ----
__global__ __launch_bounds__(256) void mgemm_ln_k(const bf16* __restrict__ A,
    const bf16* __restrict__ Wt, const bf16* __restrict__ bias,
    float* __restrict__ hout, int Ktot,
    const bf16* __restrict__ g, const bf16* __restrict__ bta,
    bf16* __restrict__ xnb){
  __shared__ __align__(16) bf16 As[128*32];
  __shared__ __align__(16) bf16 Bs[128*32];
  __shared__ float red[2][128][2];
  int tid = threadIdx.x;
  int rowBase = blockIdx.y * 128;
  int w = tid >> 6, lane = tid & 63, quad = lane >> 4, cl = lane & 15;
  int waveM = w >> 1, waveN = w & 1;
  f32x4 accr[4][4];
  #pragma unroll
  for (int i = 0; i < 4; i++)
    #pragma unroll
    for (int j = 0; j < 4; j++) accr[i][j] = (f32x4){0.f,0.f,0.f,0.f};
  int lr = tid >> 2, kc = tid & 3;
  const bf16* Ap = A  + (size_t)(rowBase + lr)*Ktot + kc*8;
  const bf16* Bp = Wt + (size_t)lr*Ktot + kc*8;
  bf16* AsW = As + tid*8;
  bf16* BsW = Bs + tid*8;
  for (int kk = 0; kk < Ktot; kk += 32){
    __syncthreads();
    gll16(Ap + kk, AsW);
    gll16(Ap + (size_t)64*Ktot + kk, AsW + 64*32);
    gll16(Bp + kk, BsW);
    gll16(Bp + (size_t)64*Ktot + kk, BsW + 64*32);
    __syncthreads();
    bf16x8 af[4], bfr[4];
    #pragma unroll
    for (int mi = 0; mi < 4; mi++)
      af[mi] = *(const bf16x8*)(As + (waveM*64 + mi*16 + cl)*32 + quad*8);
    #pragma unroll
    for (int nj = 0; nj < 4; nj++)
      bfr[nj] = *(const bf16x8*)(Bs + (waveN*64 + nj*16 + cl)*32 + quad*8);
    #pragma unroll
    for (int mi = 0; mi < 4; mi++)
      #pragma unroll
      for (int nj = 0; nj < 4; nj++)
        accr[mi][nj] = __builtin_amdgcn_mfma_f32_16x16x32_bf16(af[mi], bfr[nj], accr[mi][nj], 0,0,0);
  }
  int colW = waveN*64;
  float bv[4];
  #pragma unroll
  for (int nj = 0; nj < 4; nj++)
    bv[nj] = bias ? b2f(bias[colW + nj*16 + cl]) : 0.0f;
  float hv[4][4][4];
  float psum[4][4], psq[4][4];
  #pragma unroll
  for (int mi = 0; mi < 4; mi++)
    #pragma unroll
    for (int r = 0; r < 4; r++){ psum[mi][r] = 0.f; psq[mi][r] = 0.f; }
  #pragma unroll
  for (int mi = 0; mi < 4; mi++){
    #pragma unroll
    for (int r = 0; r < 4; r++){
      int row = rowBase + waveM*64 + mi*16 + quad*4 + r;
      #pragma unroll
      for (int nj = 0; nj < 4; nj++){
        int col = colW + nj*16 + cl;
        size_t idx = (size_t)row*D_ + col;
        float v = hout[idx] + accr[mi][nj][r] + bv[nj];
        hout[idx] = v;
        hv[mi][nj][r] = v;
        psum[mi][r] += v; psq[mi][r] += v*v;
      }
    }
  }
  if (g){
    #pragma unroll
    for (int off = 1; off <= 8; off <<= 1)
      #pragma unroll
      for (int mi = 0; mi < 4; mi++)
        #pragma unroll
        for (int r = 0; r < 4; r++){
          psum[mi][r] += __shfl_xor(psum[mi][r], off, 64);
          psq[mi][r]  += __shfl_xor(psq[mi][r],  off, 64);
        }
    if (cl == 0){
      #pragma unroll
      for (int mi = 0; mi < 4; mi++)
        #pragma unroll
        for (int r = 0; r < 4; r++){
          int rl = waveM*64 + mi*16 + quad*4 + r;
          red[waveN][rl][0] = psum[mi][r];
          red[waveN][rl][1] = psq[mi][r];
        }
    }
    __syncthreads();
    float gv[4], btv[4];
    #pragma unroll
    for (int nj = 0; nj < 4; nj++){
      int col = colW + nj*16 + cl;
      gv[nj] = b2f(g[col]); btv[nj] = b2f(bta[col]);
    }
    #pragma unroll
    for (int mi = 0; mi < 4; mi++){
      #pragma unroll
      for (int r = 0; r < 4; r++){
        int rl = waveM*64 + mi*16 + quad*4 + r;
        float s = red[0][rl][0] + red[1][rl][0];
        float q = red[0][rl][1] + red[1][rl][1];
        float mean = s*(1.0f/128.0f);
        float var  = q*(1.0f/128.0f) - mean*mean;
        float rstd = rsqrtf(var + 1e-5f);
        int row = rowBase + rl;
        #pragma unroll
        for (int nj = 0; nj < 4; nj++){
          int col = colW + nj*16 + cl;
          xnb[(size_t)row*D_ + col] = f2b((hv[mi][nj][r]-mean)*rstd*gv[nj] + btv[nj]);
        }
      }
    }
  }
}

// ---- fused FFN: h += relu(xn@W1+b1)@W2 + b2; xnb = LN(h) ----
// A-fragments read directly from global (L1/L2-resident 32KB tile) — no As LDS.
// LDS ~45KB -> 3 blocks/CU.
__global__ __launch_bounds__(256,3) void mffn_ln_k(const bf16* __restrict__ A,
    const bf16* __restrict__ W1t, const bf16* __restrict__ b1,
    const bf16* __restrict__ W2t, const bf16* __restrict__ b2,
    float* __restrict__ hout,
    const bf16* __restrict__ g, const bf16* __restrict__ bta,
    bf16* __restrict__ xnb){
  __shared__ __align__(16) bf16 Hs[128*136];   // hidden chunk (pad 8)
  __shared__ __align__(16) bf16 Bs[128*32];    // weight k-step tile
  __shared__ float red[2][128][2];
  int tid = threadIdx.x;
  int rowBase = blockIdx.x * 128;
  int w = tid >> 6, lane = tid & 63, quad = lane >> 4, cl = lane & 15;
  int waveM = w >> 1, waveN = w & 1;
  f32x4 acc2[4][4];
  #pragma unroll
  for (int i = 0; i < 4; i++)
    #pragma unroll
    for (int j = 0; j < 4; j++) acc2[i][j] = (f32x4){0.f,0.f,0.f,0.f};
  int lr = tid >> 2, kc = tid & 3;
  bf16* BsW = Bs + tid*8;
  int aRow0 = waveM*64;
  for (int kt = 0; kt < 4; kt++){
    // ---- FFN1 chunk: hidden[:,kt*128 .. +128) ----
    f32x4 acc1[4][4];
    #pragma unroll
    for (int i = 0; i < 4; i++)
      #pragma unroll
      for (int j = 0; j < 4; j++) acc1[i][j] = (f32x4){0.f,0.f,0.f,0.f};
    for (int ks = 0; ks < 4; ks++){
      __syncthreads();
      gll16(W1t + (size_t)(kt*128 + lr)*128 + ks*32 + kc*8, BsW);
      gll16(W1t + (size_t)(kt*128 + 64 + lr)*128 + ks*32 + kc*8, BsW + 64*32);
      __syncthreads();
      bf16x8 af[4], bfr[4];
      #pragma unroll
      for (int mi = 0; mi < 4; mi++)
        af[mi] = *(const bf16x8*)(A + (size_t)(rowBase + aRow0 + mi*16 + cl)*128 + ks*32 + quad*8);
      #pragma unroll
      for (int nj = 0; nj < 4; nj++)
        bfr[nj] = *(const bf16x8*)(Bs + (waveN*64 + nj*16 + cl)*32 + quad*8);
      #pragma unroll
      for (int mi = 0; mi < 4; mi++)
        #pragma unroll
        for (int nj = 0; nj < 4; nj++)
          acc1[mi][nj] = __builtin_amdgcn_mfma_f32_16x16x32_bf16(af[mi], bfr[nj], acc1[mi][nj], 0,0,0);
    }
    // bias + relu -> Hs (bf16)
    float b1v[4];
    #pragma unroll
    for (int nj = 0; nj < 4; nj++)
      b1v[nj] = b2f(b1[kt*128 + waveN*64 + nj*16 + cl]);
    #pragma unroll
    for (int mi = 0; mi < 4; mi++){
      #pragma unroll
      for (int r = 0; r < 4; r++){
        int row = aRow0 + mi*16 + quad*4 + r;
        #pragma unroll
        for (int nj = 0; nj < 4; nj++){
          int col = waveN*64 + nj*16 + cl;
          Hs[row*136 + col] = f2b(fmaxf(acc1[mi][nj][r] + b1v[nj], 0.0f));
        }
      }
    }
    // ---- FFN2 partial: out += hidden_chunk @ W2[kt*128.., :] ----
    for (int ks = 0; ks < 4; ks++){
      __syncthreads();   // Hs visible (first iter) / Bs WAR
      gll16(W2t + (size_t)lr*512 + kt*128 + ks*32 + kc*8, BsW);
      gll16(W2t + (size_t)(64 + lr)*512 + kt*128 + ks*32 + kc*8, BsW + 64*32);
      __syncthreads();
      bf16x8 af[4], bfr[4];
      #pragma unroll
      for (int mi = 0; mi < 4; mi++)
        af[mi] = *(const bf16x8*)(Hs + (aRow0 + mi*16 + cl)*136 + ks*32 + quad*8);
      #pragma unroll
      for (int nj = 0; nj < 4; nj++)
        bfr[nj] = *(const bf16x8*)(Bs + (waveN*64 + nj*16 + cl)*32 + quad*8);
      #pragma unroll
      for (int mi = 0; mi < 4; mi++)
        #pragma unroll
        for (int nj = 0; nj < 4; nj++)
          acc2[mi][nj] = __builtin_amdgcn_mfma_f32_16x16x32_bf16(af[mi], bfr[nj], acc2[mi][nj], 0,0,0);
    }
    __syncthreads();    // Hs WAR before next kt overwrites
  }
  // ---- epilogue: bias2 + residual-acc + fused LN ----
  int colW = waveN*64;
  float bv[4];
  #pragma unroll
  for (int nj = 0; nj < 4; nj++)
    bv[nj] = b2f(b2[colW + nj*16 + cl]);
  float hv[4][4][4];
  float psum[4][4], psq[4][4];
  #pragma unroll
  for (int mi = 0; mi < 4; mi++)
    #pragma unroll
    for (int r = 0; r < 4; r++){ psum[mi][r] = 0.f; psq[mi][r] = 0.f; }
  #pragma unroll
  for (int mi = 0; mi < 4; mi++){
    #pragma unroll
    for (int r = 0; r < 4; r++){
      int row = rowBase + aRow0 + mi*16 + quad*4 + r;
      #pragma unroll
      for (int nj = 0; nj < 4; nj++){
        int col = colW + nj*16 + cl;
        size_t idx = (size_t)row*D_ + col;
        float v = hout[idx] + acc2[mi][nj][r] + bv[nj];
        hout[idx] = v;
        hv[mi][nj][r] = v;
        psum[mi][r] += v; psq[mi][r] += v*v;
      }
    }
  }
  if (g){
    #pragma unroll
    for (int off = 1; off <= 8; off <<= 1)
      #pragma unroll
      for (int mi = 0; mi < 4; mi++)
        #pragma unroll
        for (int r = 0; r < 4; r++){
          psum[mi][r] += __shfl_xor(psum[mi][r], off, 64);
          psq[mi][r]  += __shfl_xor(psq[mi][r],  off, 64);
        }
    if (cl == 0){
      #pragma unroll
      for (int mi = 0; mi < 4; mi++)
        #pragma unroll
        for (int r = 0; r < 4; r++){
          int rl = aRow0 + mi*16 + quad*4 + r;
          red[waveN][rl][0] = psum[mi][r];
          red[waveN][rl][1] = psq[mi][r];
        }
    }
    __syncthreads();
    float gv[4], btv[4];
    #pragma unroll
    for (int nj = 0; nj < 4; nj++){
      int col = colW + nj*16 + cl;
      gv[nj] = b2f(g[col]); btv[nj] = b2f(bta[col]);
    }
    #pragma unroll
    for (int mi = 0; mi < 4; mi++){
      #pragma unroll
      for (int r = 0; r < 4; r++){
        int rl = aRow0 + mi*16 + quad*4 + r;
        float s = red[0][rl][0] + red[1][rl][0];
        float q = red[0][rl][1] + red[1][rl][1];
        float mean = s*(1.0f/128.0f);
        float var  = q*(1.0f/128.0f) - mean*mean;
        float rstd = rsqrtf(var + 1e-5f);
        int row = rowBase + rl;
        #pragma unroll
        for (int nj = 0; nj < 4; nj++){
          int col = colW + nj*16 + cl;
          xnb[(size_t)row*D_ + col] = f2b((hv[mi][nj][r]-mean)*rstd*gv[nj] + btv[nj]);
        }
      }
    }
  }
}

// ---- MFMA spatial attention (round-10 version) ----
__global__ __launch_bounds__(256,4) void sattn_k(const bf16* __restrict__ sQ,
    const bf16* __restrict__ sK, const bf16* __restrict__ sV,
    const float* __restrict__ maskg, bf16* __restrict__ ob){
  __shared__ __align__(16) _Float16 Vt[16*KVH];
  __shared__ __align__(16) _Float16 Ps[4*16*KVH];
  int tid = threadIdx.x;
  int bid = blockIdx.x;                // slab = (b*T+t)*H + hh
  int hh = bid & 7; int bt = bid >> 3; int t = bt % T_; int b = bt / T_;
  const bf16* Kslab = sK + (size_t)bid*SLAB;
  const bf16* Vslab = sV + (size_t)bid*SLAB;
  const bf16* Qslab = sQ + (size_t)bid*SLAB;
  for (int i = tid; i < 16*25; i += 256){ int d = i/25, c = 207 + i%25; Vt[d*KVH + c] = (_Float16)0.0f; }
  for (int i = tid; i < 64*24; i += 256){ int row = i/24, c = 208 + i%24; Ps[row*KVH + c] = (_Float16)0.0f; }
  for (int i = tid; i < SLAB; i += 256){
    int n = i >> 4, d = i & 15;
    Vt[d*KVH + n] = (_Float16)b2f(Vslab[i]);
  }
  __syncthreads();

  int lane = tid & 63, w = tid >> 6, quad = lane >> 4, cl = lane & 15;
  f16x8 ones8;
  #pragma unroll
  for (int j = 0; j < 8; j++) ones8[j] = (_Float16)1.0f;
  int nstripes = (w == 0) ? 4 : 3;
  for (int si = 0; si < nstripes; si++){
    int mi = w + si*4;
    bf16x8 aq = (bf16x8){0,0,0,0,0,0,0,0};
    {
      int n = mi*16 + cl; if (n > N_-1) n = N_-1;
      if (quad < 2) aq = *(const bf16x8*)(Qslab + n*16 + quad*8);
    }
    const float* mrow = maskg + ((size_t)mi*13)*256 + lane*4;
    f32x4 s[13];
    #pragma unroll
    for (int nj = 0; nj < 13; nj++){
      bf16x8 bk = (bf16x8){0,0,0,0,0,0,0,0};
      if (quad < 2){
        int nb = nj*16 + cl; if (nb > N_-1) nb = N_-1;
        bk = *(const bf16x8*)(Kslab + nb*16 + quad*8);
      }
      f32x4 c0 = *(const f32x4*)(mrow + nj*256);
      s[nj] = __builtin_amdgcn_mfma_f32_16x16x32_bf16(aq, bk, c0, 0,0,0);
    }
    int row0 = mi*16 + quad*4;
    _Float16* Pw = Ps + w*16*KVH;
    #pragma unroll
    for (int r = 0; r < 4; r++){
      _Float16* Pr = Pw + (quad*4 + r)*KVH;
      #pragma unroll
      for (int nj = 0; nj < 13; nj++)
        Pr[nj*16 + cl] = (_Float16)exp2f(s[nj][r]);
    }
    __threadfence_block();
    f32x4 o = {0.f,0.f,0.f,0.f};
    f32x4 osum = {0.f,0.f,0.f,0.f};
    #pragma unroll
    for (int kt = 0; kt < 7; kt++){
      f16x8 ap = *(const f16x8*)(Pw + cl*KVH + kt*32 + quad*8);
      f16x8 bv = *(const f16x8*)(Vt + cl*KVH + kt*32 + quad*8);
      o    = __builtin_amdgcn_mfma_f32_16x16x32_f16(ap, bv,    o,    0,0,0);
      osum = __builtin_amdgcn_mfma_f32_16x16x32_f16(ap, ones8, osum, 0,0,0);
    }
    #pragma unroll
    for (int r = 0; r < 4; r++){
      int rg = row0 + r;
      if (rg < N_)
        ob[((size_t)((b*N_ + rg)*T_ + t))*D_ + hh*HD_ + cl] = f2b(o[r]/osum[r]);
    }
    __threadfence_block();
  }
}

// ---- temporal attention ----
__global__ void tattn_k(const bf16* qkv, bf16* ob){
  int bid = blockIdx.x; int b = bid / N_, n = bid % N_;
  __shared__ float qs[T_*D_];
  __shared__ float ks[T_*D_];
  __shared__ float vs[T_*D_];
  size_t rowb = ((size_t)(b*N_+n)*T_)*384;
  const u32* src = (const u32*)(qkv + rowb);
  for (int idx = threadIdx.x; idx < T_*192; idx += 128){
    int tt = idx / 192, cw = idx - tt*192;
    u32 pr = src[tt*192 + cw];
    union { u32 u; bf16 b[2]; } cv; cv.u = pr;
    float v0 = b2f(cv.b[0]), v1 = b2f(cv.b[1]);
    int arr = cw >> 6, cp2 = (cw & 63)*2;
    float* dst = (arr == 0) ? qs : (arr == 1) ? ks : vs;
    dst[tt*128 + cp2] = v0; dst[tt*128 + cp2 + 1] = v1;
  }
  __syncthreads();
  int p = threadIdx.x;
  if (p < H_*T_){
    int hh = p / T_, t = p - hh*T_;
    float qreg[16];
    for (int d = 0; d < 16; d++) qreg[d] = qs[t*128 + hh*16 + d];
    float sc[12]; float mx = -3.4e38f;
    for (int s = 0; s < 12; s++){
      float a = 0.0f;
      for (int d = 0; d < 16; d++) a += qreg[d]*ks[s*128 + hh*16 + d];
      a = (s <= t) ? a*SCALE_ : -3.4e38f;
      sc[s] = a; mx = fmaxf(mx, a);
    }
    float ssum = 0.0f;
    for (int s = 0; s < 12; s++){
      float e = (s <= t) ? __expf(sc[s]-mx) : 0.0f;
      sc[s] = e; ssum += e;
    }
    float inv = 1.0f/ssum;
    size_t obase = ((size_t)(b*N_+n)*T_ + t)*D_ + hh*16;
    for (int d = 0; d < 16; d++){
      float acc = 0.0f;
      for (int s = 0; s < 12; s++) acc += sc[s]*vs[s*128 + hh*16 + d];
      ob[obase + d] = f2b(acc*inv);
    }
  }
}

// ---- VALU GEMM for small head GEMMs ----
__global__ void gemm_k(const bf16* A, int lda, const bf16* W, const bf16* bias,
                       void* outp, int ldo, int M, int Ncols, int K, int relu, int acc){
  __shared__ float Ast[16*68];
  __shared__ float Ws [16*68];
  int tx = threadIdx.x & 15, ty = threadIdx.x >> 4;
  int rowBase = blockIdx.y * 64, colBase = blockIdx.x * 64;
  float accr[4][4];
  for (int i = 0; i < 4; i++) for (int j = 0; j < 4; j++) accr[i][j] = 0.0f;
  for (int kk = 0; kk < K; kk += 16){
    int kq = threadIdx.x & 15, r0 = threadIdx.x >> 4;
    for (int it = 0; it < 4; it++){
      int r = r0 + it*16, row = rowBase + r;
      float v = 0.0f;
      if (row < M) v = b2f(A[(size_t)row*lda + kk + kq]);
      Ast[kq*68 + r] = v;
    }
    int c = threadIdx.x & 63, w0 = threadIdx.x >> 6;
    for (int it = 0; it < 4; it++){
      int kr = w0 + it*4;
      Ws[kr*68 + c] = b2f(W[(size_t)(kk+kr)*Ncols + colBase + c]);
    }
    __syncthreads();
    for (int k = 0; k < 16; k++){
      float av[4], wv[4];
      for (int i = 0; i < 4; i++) av[i] = Ast[k*68 + ty*4 + i];
      for (int j = 0; j < 4; j++) wv[j] = Ws[k*68 + tx*4 + j];
      for (int i = 0; i < 4; i++)
        for (int j = 0; j < 4; j++) accr[i][j] += av[i]*wv[j];
    }
    __syncthreads();
  }
  for (int i = 0; i < 4; i++){
    int row = rowBase + ty*4 + i;
    if (row >= M) continue;
    for (int j = 0; j < 4; j++){
      int col = colBase + tx*4 + j;
      float v = accr[i][j];
      if (bias) v += b2f(bias[col]);
      if (relu) v = fmaxf(v, 0.0f);
      if (acc) ((float*)outp)[(size_t)row*ldo + col] += v;
      else     ((bf16*)outp)[(size_t)row*ldo + col] = f2b(v);
    }
  }
}

__global__ void gather_k(const float* h, bf16* hlb){
  int i = blockIdx.x*256 + threadIdx.x;
  if (i >= ROWS2*D_) return;
  int r = i >> 7, d = i & 127;
  hlb[i] = f2b(h[((size_t)r*T_ + (T_-1))*D_ + d]);
}

__global__ void head3_k(const bf16* z2, const bf16* P3, const bf16* Pb3,
                        void* out, int out_n, const int* flag){
  int i = blockIdx.x*256 + threadIdx.x;
  if (i >= out_n) return;
  int r = i / PL_, j = i - r*PL_;
  float acc = b2f(Pb3[j]);
  for (int d = 0; d < 128; d++) acc += b2f(z2[(size_t)r*128 + d]) * b2f(P3[d*PL_ + j]);
  if (*flag) ((bf16*)out)[i] = f2b(acc);
  else       ((float*)out)[i] = acc;
}

extern "C" void kernel_launch(void* const* d_in, const int* in_sizes, int n_in,
                              void* d_out, int out_size, void* d_ws, size_t ws_size,
                              hipStream_t stream){
  size_t HB = (size_t)TOK*D_*4;
  size_t XB = (size_t)TOK*D_*2;
  size_t RB = (size_t)TOK*D_*8;
  float* h    = (float*)d_ws;
  bf16*  xnb  = (bf16*)((char*)d_ws + HB);
  bf16*  reg_ = (bf16*)((char*)d_ws + HB + XB);
  bf16*  cvt  = (bf16*)((char*)d_ws + HB + XB + RB);
  bf16*  wsb  = (bf16*)d_ws;
  const int FIDX[34] = {0,2,3,4,5,6,7,8,9,10,11,12,13,14,15,16,17,18,19,20,
                        21,22,23,24,25,26,27,28,29,30,31,32,33,34};
  bf16* cp[34];
  size_t off = 0;
  for (int i = 0; i < 34; i++){ cp[i] = cvt + off; off += (size_t)in_sizes[FIDX[i]]; }
  char* tail   = (char*)d_ws + HB + XB + RB + ((off*2 + 255) & ~(size_t)255);
  float* maskg = (float*)tail;
  bf16* qkvw   = (bf16*)(tail + (size_t)MSK_N*4);
  int*  flag   = (int*)(tail + (size_t)MSK_N*4 + (size_t)L_*384*128*2);

  const bf16 *x_c=cp[0], *Wi_c=cp[1], *bi_c=cp[2],
             *Wo_t=cp[6], *bo_c=cp[7], *sW1_t=cp[8], *sB1_c=cp[9], *sW2_t=cp[10], *sB2_c=cp[11],
             *sg1_c=cp[12], *sh1_c=cp[13], *sg2_c=cp[14], *sh2_c=cp[15], *Win_t=cp[16], *Bin_c=cp[17],
             *Wout_t=cp[18], *Bout_c=cp[19], *tW1_t=cp[20], *tB1_c=cp[21], *tW2_t=cp[22], *tB2_c=cp[23],
             *tg1_c=cp[24], *th1_c=cp[25], *tg2_c=cp[26], *th2_c=cp[27], *P1_c=cp[28], *Pb1_c=cp[29],
             *P2_c=cp[30], *Pb2_c=cp[31], *P3_c=cp[32], *Pb3_c=cp[33];
  const int* adj = (const int*)d_in[1];

  bf16* sQ   = reg_;
  bf16* sK   = reg_ + (size_t)TOK*128;
  bf16* sV   = reg_ + (size_t)2*TOK*128;
  bf16* ob   = reg_ + (size_t)3*TOK*128;
  bf16* qkvb = reg_;

  detect_k<<<1, 256, 0, stream>>>(d_in[0], flag);

  {
    const int FLAT[24] = {0,1,2,7,9,11,12,13,14,15,17,19,21,23,24,25,26,27,28,29,30,31,32,33};
    FlatArgs fa; int c = 0;
    for (int ii = 0; ii < 24; ii++){
      int ci = FLAT[ii];
      fa.src[ii] = d_in[FIDX[ci]];
      fa.dst[ii] = (long long)(cp[ci] - wsb);
      fa.cum[ii] = c;
      c += in_sizes[FIDX[ci]];
    }
    fa.cum[24] = c;
    cvt_flat_k<<<(c+255)/256, 256, 0, stream>>>(fa, wsb, flag, c);
  }
  {
    TArgs ta; int c = 0;
    const void* srcs[10] = {d_in[4], d_in[5], d_in[6], d_in[7], d_in[9], d_in[11],
                            d_in[17], d_in[19], d_in[21], d_in[23]};
    bf16* dsts[10] = {qkvw, qkvw, qkvw, cp[6], cp[8], cp[10], cp[16], cp[18], cp[20], cp[22]};
    int Ks_[10]   = {128,128,128, 128, 128, 512, 128, 128, 128, 512};
    int Ncs[10]   = {128,128,128, 128, 512, 128, 384, 128, 512, 128};
    int Lst[10]   = {384*128,384*128,384*128, 128*128, 128*512, 512*128, 128*384, 128*128, 128*512, 512*128};
    int ros[10]   = {0,128,256, 0,0,0, 0,0,0, 0};
    for (int j = 0; j < 10; j++){
      ta.src[j] = srcs[j];
      ta.dst[j] = (long long)(dsts[j] - wsb);
      ta.K[j] = Ks_[j]; ta.Nc[j] = Ncs[j]; ta.Lstr[j] = Lst[j]; ta.ro[j] = ros[j];
      ta.scale[j] = (j == 0) ? SCALE_*LOG2E_ : 1.0f;
      ta.cum[j] = c;
      c += L_*Ks_[j]*Ncs[j];
    }
    ta.cum[10] = c;
    cvt_t_k<<<(c+255)/256, 256, 0, stream>>>(ta, wsb, flag, c);
  }
  maskc_k<<<(MSK_N+255)/256, 256, 0, stream>>>(adj, maskg);
  embed_ln_k<<<TOK/4, 256, 0, stream>>>(x_c, Wi_c, bi_c, sg1_c, sh1_c, h, xnb);

  const dim3 gP  (1, TOK/128);
  const dim3 gQKV(3, TOK/128);

  for (int l = 0; l < L_; l++){
    // spatial attention
    mgemm_qkvT_k<<<gQKV, 256, 0, stream>>>(xnb, qkvw + (size_t)l*384*128, sQ, sK, sV);
    sattn_k<<<B_*T_*H_, 256, 0, stream>>>(sQ, sK, sV, maskg, ob);
    mgemm_ln_k<<<gP, 256, 0, stream>>>(ob, Wo_t + (size_t)l*D_*D_, bo_c + l*D_, h, D_,
                                       sg2_c + l*D_, sh2_c + l*D_, xnb);
    // fused FFN 1 (-> LN tg1)
    mffn_ln_k<<<TOK/128, 256, 0, stream>>>(xnb, sW1_t + (size_t)l*D_*FF_, sB1_c + l*FF_,
                                           sW2_t + (size_t)l*FF_*D_, sB2_c + l*D_, h,
                                           tg1_c + l*D_, th1_c + l*D_, xnb);
    // temporal attention
    mgemm_k<<<gQKV, 256, 0, stream>>>(xnb, Win_t + (size_t)l*D_*384, Bin_c + l*384, qkvb, 384, D_, 0);
    tattn_k<<<B_*N_, 128, 0, stream>>>(qkvb, ob);
    mgemm_ln_k<<<gP, 256, 0, stream>>>(ob, Wout_t + (size_t)l*D_*D_, Bout_c + l*D_, h, D_,
                                       tg2_c + l*D_, th2_c + l*D_, xnb);
    // fused FFN 2 (-> LN next sg1 or none)
    const bf16* gnext = (l < L_-1) ? (sg1_c + (l+1)*D_) : nullptr;
    const bf16* bnext = (l < L_-1) ? (sh1_c + (l+1)*D_) : nullptr;
    mffn_ln_k<<<TOK/128, 256, 0, stream>>>(xnb, tW1_t + (size_t)l*D_*FF_, tB1_c + l*FF_,
                                           tW2_t + (size_t)l*FF_*D_, tB2_c + l*D_, h,
                                           gnext, bnext, xnb);
  }

  // head
  bf16* hlb = reg_;
  bf16* z1  = reg_ + (size_t)ROWS2*128;
  bf16* z2  = z1   + (size_t)ROWS2*256;
  gather_k<<<(ROWS2*D_)/256, 256, 0, stream>>>(h, hlb);
  gemm_k<<<dim3(256/64, (ROWS2+63)/64), 256, 0, stream>>>(hlb, 128, P1_c, Pb1_c, z1, 256, ROWS2, 256, 128, 1, 0);
  gemm_k<<<dim3(128/64, (ROWS2+63)/64), 256, 0, stream>>>(z1, 256, P2_c, Pb2_c, z2, 128, ROWS2, 128, 256, 1, 0);
  head3_k<<<(out_size+255)/256, 256, 0, stream>>>(z2, P3_c, Pb3_c, d_out, out_size, flag);
}

// Round 13
// 1756.436 us; speedup vs baseline: 1.0442x; 1.0442x over previous
//
#include <hip/hip_runtime.h>
#include <hip/hip_bf16.h>

#define B_   32
#define N_   207
#define T_   12
#define D_   128
#define H_   8
#define HD_  16
#define L_   4
#define FF_  512
#define PL_  12
#define TOK  (B_*N_*T_)      // 79488 = 621*128
#define ROWS2 (B_*N_)        // 6624
#define SCALE_ 0.25f
#define LOG2E_ 1.4426950408889634f
#define NEG2_ -1.4426950409e9f   // -1e9 in log2 domain
#define KVH  232             // Vt/P row stride (fp16)
#define SLAB 3312            // 207*16 elements per (b,t,h) slab
#define MSK_N (13*13*256)    // mask elements in C-frag layout

typedef __hip_bfloat16 bf16;
typedef unsigned int u32;
typedef __attribute__((ext_vector_type(4))) unsigned int u32x4;
typedef __attribute__((ext_vector_type(8))) short bf16x8;     // 8 bf16 (MFMA A/B frag)
typedef __attribute__((ext_vector_type(8))) _Float16 f16x8;   // 8 fp16 (MFMA A/B frag)
typedef __attribute__((ext_vector_type(4))) float f32x4;      // MFMA C/D frag

__device__ __forceinline__ float b2f(bf16 x){ return __bfloat162float(x); }
__device__ __forceinline__ bf16  f2b(float x){ return __float2bfloat16(x); }

// async global->LDS 16B per lane (dest must be wave-uniform base + lane*16)
__device__ __forceinline__ void gll16(const bf16* g, bf16* l){
  __builtin_amdgcn_global_load_lds((const __attribute__((address_space(1))) void*)g,
                                   (__attribute__((address_space(3))) void*)l, 16, 0, 0);
}

// ---- dtype detection ----
__global__ void detect_k(const void* x, int* flag){
  __shared__ int cnt[256];
  const unsigned short* u = (const unsigned short*)x;
  int ok = 0;
  for (int i = threadIdx.x; i < 4096; i += 256){
    unsigned int bits = ((unsigned int)u[i]) << 16;
    float f = __uint_as_float(bits);
    float a = fabsf(f);
    if (f == 0.0f || (a > 1e-4f && a < 64.0f)) ok++;
  }
  cnt[threadIdx.x] = ok;
  __syncthreads();
  for (int s = 128; s > 0; s >>= 1){
    if (threadIdx.x < s) cnt[threadIdx.x] += cnt[threadIdx.x + s];
    __syncthreads();
  }
  if (threadIdx.x == 0) *flag = (cnt[0] > 3686) ? 1 : 0;
}

// ---- batched flat convert ----
struct FlatArgs {
  const void* src[24];
  long long dst[24];
  int cum[25];
};
__global__ void cvt_flat_k(FlatArgs a, bf16* base, const int* flag, int total){
  int i = blockIdx.x*256 + threadIdx.x;
  if (i >= total) return;
  int j = 0;
  while (i >= a.cum[j+1]) j++;
  int loc = i - a.cum[j];
  float v = (*flag) ? b2f(((const bf16*)a.src[j])[loc]) : ((const float*)a.src[j])[loc];
  base[a.dst[j] + loc] = f2b(v);
}

// ---- batched transpose convert (with per-segment scale) ----
struct TArgs {
  const void* src[10];
  long long dst[10];
  int K[10], Nc[10], Lstr[10], ro[10];
  float scale[10];
  int cum[11];
};
__global__ void cvt_t_k(TArgs a, bf16* base, const int* flag, int total){
  int i = blockIdx.x*256 + threadIdx.x;
  if (i >= total) return;
  int j = 0;
  while (i >= a.cum[j+1]) j++;
  int loc = i - a.cum[j];
  int KN = a.K[j]*a.Nc[j];
  int l = loc / KN; int rm = loc - l*KN; int k = rm / a.Nc[j]; int n = rm - k*a.Nc[j];
  float v = (*flag) ? b2f(((const bf16*)a.src[j])[loc]) : ((const float*)a.src[j])[loc];
  base[a.dst[j] + (long long)l*a.Lstr[j] + (long long)(a.ro[j]+n)*a.K[j] + k] = f2b(v*a.scale[j]);
}

// ---- additive mask in MFMA C-fragment layout (log2 domain) ----
__global__ void maskc_k(const int* adj, float* maskg){
  int i = blockIdx.x*256 + threadIdx.x;
  if (i >= MSK_N) return;
  int cell = i >> 8;             // mi*13+nj
  int mi = cell / 13, nj = cell - mi*13;
  int rem = i & 255;
  int lane = rem >> 2, r = rem & 3;
  int quad = lane >> 4, cl = lane & 15;
  int row = mi*16 + quad*4 + r; if (row > 206) row = 206;
  int col = nj*16 + cl;
  float v;
  if (col > 206) v = -1e30f;
  else v = adj[row*N_ + col] ? 0.0f : NEG2_;
  maskg[i] = v;
}

// ---- embed + fused LN (layer 0) ----
__global__ void embed_ln_k(const bf16* x, const bf16* Wi, const bf16* bi,
                           const bf16* g, const bf16* bta, float* h, bf16* xnb){
  int wave = threadIdx.x >> 6, lane = threadIdx.x & 63;
  int tok = blockIdx.x*4 + wave;
  if (tok >= TOK) return;
  float xv = b2f(x[tok]);
  float v0 = xv*b2f(Wi[lane])    + b2f(bi[lane]);
  float v1 = xv*b2f(Wi[lane+64]) + b2f(bi[lane+64]);
  float* hp = h + (size_t)tok*D_;
  hp[lane] = v0; hp[lane+64] = v1;
  float s = v0 + v1;
  for (int off = 32; off >= 1; off >>= 1) s += __shfl_xor(s, off, 64);
  float m = s * (1.0f/128.0f);
  float d0 = v0 - m, d1 = v1 - m;
  float vv = d0*d0 + d1*d1;
  for (int off = 32; off >= 1; off >>= 1) vv += __shfl_xor(vv, off, 64);
  float r = rsqrtf(vv*(1.0f/128.0f) + 1e-5f);
  bf16* op = xnb + (size_t)tok*D_;
  op[lane]    = f2b(d0*r*b2f(g[lane])    + b2f(bta[lane]));
  op[lane+64] = f2b(d1*r*b2f(g[lane+64]) + b2f(bta[lane+64]));
}

// ---- MFMA GEMM (non-acc), global_load_lds staging ----
__global__ __launch_bounds__(256) void mgemm_k(const bf16* __restrict__ A,
    const bf16* __restrict__ Wt, const bf16* __restrict__ bias,
    bf16* __restrict__ outp, int ldo, int Ktot, int relu){
  __shared__ __align__(16) bf16 As[128*32];
  __shared__ __align__(16) bf16 Bs[128*32];
  int tid = threadIdx.x;
  int rowBase = blockIdx.y * 128, colBase = blockIdx.x * 128;
  int w = tid >> 6, lane = tid & 63, quad = lane >> 4, cl = lane & 15;
  int waveM = w >> 1, waveN = w & 1;
  f32x4 accr[4][4];
  #pragma unroll
  for (int i = 0; i < 4; i++)
    #pragma unroll
    for (int j = 0; j < 4; j++) accr[i][j] = (f32x4){0.f,0.f,0.f,0.f};
  int lr = tid >> 2, kc = tid & 3;
  const bf16* Ap = A  + (size_t)(rowBase + lr)*Ktot + kc*8;
  const bf16* Bp = Wt + (size_t)(colBase + lr)*Ktot + kc*8;
  bf16* AsW = As + tid*8;
  bf16* BsW = Bs + tid*8;
  for (int kk = 0; kk < Ktot; kk += 32){
    __syncthreads();
    gll16(Ap + kk, AsW);
    gll16(Ap + (size_t)64*Ktot + kk, AsW + 64*32);
    gll16(Bp + kk, BsW);
    gll16(Bp + (size_t)64*Ktot + kk, BsW + 64*32);
    __syncthreads();
    bf16x8 af[4], bfr[4];
    #pragma unroll
    for (int mi = 0; mi < 4; mi++)
      af[mi] = *(const bf16x8*)(As + (waveM*64 + mi*16 + cl)*32 + quad*8);
    #pragma unroll
    for (int nj = 0; nj < 4; nj++)
      bfr[nj] = *(const bf16x8*)(Bs + (waveN*64 + nj*16 + cl)*32 + quad*8);
    #pragma unroll
    for (int mi = 0; mi < 4; mi++)
      #pragma unroll
      for (int nj = 0; nj < 4; nj++)
        accr[mi][nj] = __builtin_amdgcn_mfma_f32_16x16x32_bf16(af[mi], bfr[nj], accr[mi][nj], 0,0,0);
  }
  float bv[4];
  #pragma unroll
  for (int nj = 0; nj < 4; nj++)
    bv[nj] = bias ? b2f(bias[colBase + waveN*64 + nj*16 + cl]) : 0.0f;
  #pragma unroll
  for (int mi = 0; mi < 4; mi++){
    int row0 = rowBase + waveM*64 + mi*16 + quad*4;
    #pragma unroll
    for (int nj = 0; nj < 4; nj++){
      int col = colBase + waveN*64 + nj*16 + cl;
      #pragma unroll
      for (int r = 0; r < 4; r++){
        float v = accr[mi][nj][r] + bv[nj];
        if (relu) v = fmaxf(v, 0.0f);
        outp[(size_t)(row0+r)*ldo + col] = f2b(v);
      }
    }
  }
}

// ---- MFMA GEMM writing spatial q/k/v in [slab=(b,t,h)][n][16] layout ----
__global__ __launch_bounds__(256) void mgemm_qkvT_k(const bf16* __restrict__ A,
    const bf16* __restrict__ Wt, bf16* __restrict__ sQ,
    bf16* __restrict__ sK, bf16* __restrict__ sV){
  __shared__ __align__(16) bf16 As[128*32];
  __shared__ __align__(16) bf16 Bs[128*32];
  const int Ktot = 128;
  int tid = threadIdx.x;
  int rowBase = blockIdx.y * 128, colBase = blockIdx.x * 128;
  int w = tid >> 6, lane = tid & 63, quad = lane >> 4, cl = lane & 15;
  int waveM = w >> 1, waveN = w & 1;
  f32x4 accr[4][4];
  #pragma unroll
  for (int i = 0; i < 4; i++)
    #pragma unroll
    for (int j = 0; j < 4; j++) accr[i][j] = (f32x4){0.f,0.f,0.f,0.f};
  int lr = tid >> 2, kc = tid & 3;
  const bf16* Ap = A  + (size_t)(rowBase + lr)*Ktot + kc*8;
  const bf16* Bp = Wt + (size_t)(colBase + lr)*Ktot + kc*8;
  bf16* AsW = As + tid*8;
  bf16* BsW = Bs + tid*8;
  for (int kk = 0; kk < Ktot; kk += 32){
    __syncthreads();
    gll16(Ap + kk, AsW);
    gll16(Ap + (size_t)64*Ktot + kk, AsW + 64*32);
    gll16(Bp + kk, BsW);
    gll16(Bp + (size_t)64*Ktot + kk, BsW + 64*32);
    __syncthreads();
    bf16x8 af[4], bfr[4];
    #pragma unroll
    for (int mi = 0; mi < 4; mi++)
      af[mi] = *(const bf16x8*)(As + (waveM*64 + mi*16 + cl)*32 + quad*8);
    #pragma unroll
    for (int nj = 0; nj < 4; nj++)
      bfr[nj] = *(const bf16x8*)(Bs + (waveN*64 + nj*16 + cl)*32 + quad*8);
    #pragma unroll
    for (int mi = 0; mi < 4; mi++)
      #pragma unroll
      for (int nj = 0; nj < 4; nj++)
        accr[mi][nj] = __builtin_amdgcn_mfma_f32_16x16x32_bf16(af[mi], bfr[nj], accr[mi][nj], 0,0,0);
  }
  #pragma unroll
  for (int mi = 0; mi < 4; mi++){
    #pragma unroll
    for (int r = 0; r < 4; r++){
      int tok = rowBase + waveM*64 + mi*16 + quad*4 + r;
      int bn = tok / T_; int t = tok - bn*T_;
      int b = bn / N_;  int n = bn - b*N_;
      size_t base = ((size_t)(b*T_ + t)*H_)*SLAB + n*16 + cl;
      #pragma unroll
      for (int nj = 0; nj < 4; nj++){
        int col = colBase + waveN*64 + nj*16;
        int part = col >> 7, hh = (col >> 4) & 7;
        bf16* dst = (part == 0) ? sQ : (part == 1) ? sK : sV;
        dst[base + (size_t)hh*SLAB] = f2b(accr[mi][nj][r]);
      }
    }
  }
}

// ---- MFMA GEMM + residual-acc + fused LayerNorm (N=128, grid.x=1) ----
__global__ __launch_bounds__(256) void mgemm_ln_k(const bf16* __restrict__ A,
    const bf16* __restrict__ Wt, const bf16* __restrict__ bias,
    float* __restrict__ hout, int Ktot,
    const bf16* __restrict__ g, const bf16* __restrict__ bta,
    bf16* __restrict__ xnb){
  __shared__ __align__(16) bf16 As[128*32];
  __shared__ __align__(16) bf16 Bs[128*32];
  __shared__ float red[2][128][2];
  int tid = threadIdx.x;
  int rowBase = blockIdx.y * 128;
  int w = tid >> 6, lane = tid & 63, quad = lane >> 4, cl = lane & 15;
  int waveM = w >> 1, waveN = w & 1;
  f32x4 accr[4][4];
  #pragma unroll
  for (int i = 0; i < 4; i++)
    #pragma unroll
    for (int j = 0; j < 4; j++) accr[i][j] = (f32x4){0.f,0.f,0.f,0.f};
  int lr = tid >> 2, kc = tid & 3;
  const bf16* Ap = A  + (size_t)(rowBase + lr)*Ktot + kc*8;
  const bf16* Bp = Wt + (size_t)lr*Ktot + kc*8;
  bf16* AsW = As + tid*8;
  bf16* BsW = Bs + tid*8;
  for (int kk = 0; kk < Ktot; kk += 32){
    __syncthreads();
    gll16(Ap + kk, AsW);
    gll16(Ap + (size_t)64*Ktot + kk, AsW + 64*32);
    gll16(Bp + kk, BsW);
    gll16(Bp + (size_t)64*Ktot + kk, BsW + 64*32);
    __syncthreads();
    bf16x8 af[4], bfr[4];
    #pragma unroll
    for (int mi = 0; mi < 4; mi++)
      af[mi] = *(const bf16x8*)(As + (waveM*64 + mi*16 + cl)*32 + quad*8);
    #pragma unroll
    for (int nj = 0; nj < 4; nj++)
      bfr[nj] = *(const bf16x8*)(Bs + (waveN*64 + nj*16 + cl)*32 + quad*8);
    #pragma unroll
    for (int mi = 0; mi < 4; mi++)
      #pragma unroll
      for (int nj = 0; nj < 4; nj++)
        accr[mi][nj] = __builtin_amdgcn_mfma_f32_16x16x32_bf16(af[mi], bfr[nj], accr[mi][nj], 0,0,0);
  }
  int colW = waveN*64;
  float bv[4];
  #pragma unroll
  for (int nj = 0; nj < 4; nj++)
    bv[nj] = bias ? b2f(bias[colW + nj*16 + cl]) : 0.0f;
  float hv[4][4][4];
  float psum[4][4], psq[4][4];
  #pragma unroll
  for (int mi = 0; mi < 4; mi++)
    #pragma unroll
    for (int r = 0; r < 4; r++){ psum[mi][r] = 0.f; psq[mi][r] = 0.f; }
  #pragma unroll
  for (int mi = 0; mi < 4; mi++){
    #pragma unroll
    for (int r = 0; r < 4; r++){
      int row = rowBase + waveM*64 + mi*16 + quad*4 + r;
      #pragma unroll
      for (int nj = 0; nj < 4; nj++){
        int col = colW + nj*16 + cl;
        size_t idx = (size_t)row*D_ + col;
        float v = hout[idx] + accr[mi][nj][r] + bv[nj];
        hout[idx] = v;
        hv[mi][nj][r] = v;
        psum[mi][r] += v; psq[mi][r] += v*v;
      }
    }
  }
  if (g){
    #pragma unroll
    for (int off = 1; off <= 8; off <<= 1)
      #pragma unroll
      for (int mi = 0; mi < 4; mi++)
        #pragma unroll
        for (int r = 0; r < 4; r++){
          psum[mi][r] += __shfl_xor(psum[mi][r], off, 64);
          psq[mi][r]  += __shfl_xor(psq[mi][r],  off, 64);
        }
    if (cl == 0){
      #pragma unroll
      for (int mi = 0; mi < 4; mi++)
        #pragma unroll
        for (int r = 0; r < 4; r++){
          int rl = waveM*64 + mi*16 + quad*4 + r;
          red[waveN][rl][0] = psum[mi][r];
          red[waveN][rl][1] = psq[mi][r];
        }
    }
    __syncthreads();
    float gv[4], btv[4];
    #pragma unroll
    for (int nj = 0; nj < 4; nj++){
      int col = colW + nj*16 + cl;
      gv[nj] = b2f(g[col]); btv[nj] = b2f(bta[col]);
    }
    #pragma unroll
    for (int mi = 0; mi < 4; mi++){
      #pragma unroll
      for (int r = 0; r < 4; r++){
        int rl = waveM*64 + mi*16 + quad*4 + r;
        float s = red[0][rl][0] + red[1][rl][0];
        float q = red[0][rl][1] + red[1][rl][1];
        float mean = s*(1.0f/128.0f);
        float var  = q*(1.0f/128.0f) - mean*mean;
        float rstd = rsqrtf(var + 1e-5f);
        int row = rowBase + rl;
        #pragma unroll
        for (int nj = 0; nj < 4; nj++){
          int col = colW + nj*16 + cl;
          xnb[(size_t)row*D_ + col] = f2b((hv[mi][nj][r]-mean)*rstd*gv[nj] + btv[nj]);
        }
      }
    }
  }
}

// ---- fused FFN: h += relu(xn@W1+b1)@W2 + b2; xnb = LN(h) ----
// A staged per-(kt,ks) into a small LDS tile via global_load_lds (L2-fed DMA,
// keeps LDS reuse). LDS = Hs 34.8K + As 8K + Bs 8K = 50KB -> 3 blocks/CU.
// red[] aliases As (all As reads complete before epilogue).
__global__ __launch_bounds__(256,3) void mffn_ln_k(const bf16* __restrict__ A,
    const bf16* __restrict__ W1t, const bf16* __restrict__ b1,
    const bf16* __restrict__ W2t, const bf16* __restrict__ b2,
    float* __restrict__ hout,
    const bf16* __restrict__ g, const bf16* __restrict__ bta,
    bf16* __restrict__ xnb){
  __shared__ __align__(16) bf16 Hs[128*136];   // hidden chunk (pad 8)   34816 B
  __shared__ __align__(16) bf16 As[128*32];    // xn k-step tile          8192 B
  __shared__ __align__(16) bf16 Bs[128*32];    // weight k-step tile      8192 B
  int tid = threadIdx.x;
  int rowBase = blockIdx.x * 128;
  int w = tid >> 6, lane = tid & 63, quad = lane >> 4, cl = lane & 15;
  int waveM = w >> 1, waveN = w & 1;
  f32x4 acc2[4][4];
  #pragma unroll
  for (int i = 0; i < 4; i++)
    #pragma unroll
    for (int j = 0; j < 4; j++) acc2[i][j] = (f32x4){0.f,0.f,0.f,0.f};
  int lr = tid >> 2, kc = tid & 3;
  bf16* AsW = As + tid*8;
  bf16* BsW = Bs + tid*8;
  int aRow0 = waveM*64;
  for (int kt = 0; kt < 4; kt++){
    // ---- FFN1 chunk: hidden[:,kt*128 .. +128) ----
    f32x4 acc1[4][4];
    #pragma unroll
    for (int i = 0; i < 4; i++)
      #pragma unroll
      for (int j = 0; j < 4; j++) acc1[i][j] = (f32x4){0.f,0.f,0.f,0.f};
    for (int ks = 0; ks < 4; ks++){
      __syncthreads();
      gll16(A + (size_t)(rowBase + lr)*128 + ks*32 + kc*8, AsW);
      gll16(A + (size_t)(rowBase + 64 + lr)*128 + ks*32 + kc*8, AsW + 64*32);
      gll16(W1t + (size_t)(kt*128 + lr)*128 + ks*32 + kc*8, BsW);
      gll16(W1t + (size_t)(kt*128 + 64 + lr)*128 + ks*32 + kc*8, BsW + 64*32);
      __syncthreads();
      bf16x8 af[4], bfr[4];
      #pragma unroll
      for (int mi = 0; mi < 4; mi++)
        af[mi] = *(const bf16x8*)(As + (aRow0 + mi*16 + cl)*32 + quad*8);
      #pragma unroll
      for (int nj = 0; nj < 4; nj++)
        bfr[nj] = *(const bf16x8*)(Bs + (waveN*64 + nj*16 + cl)*32 + quad*8);
      #pragma unroll
      for (int mi = 0; mi < 4; mi++)
        #pragma unroll
        for (int nj = 0; nj < 4; nj++)
          acc1[mi][nj] = __builtin_amdgcn_mfma_f32_16x16x32_bf16(af[mi], bfr[nj], acc1[mi][nj], 0,0,0);
    }
    // bias + relu -> Hs (bf16)
    float b1v[4];
    #pragma unroll
    for (int nj = 0; nj < 4; nj++)
      b1v[nj] = b2f(b1[kt*128 + waveN*64 + nj*16 + cl]);
    #pragma unroll
    for (int mi = 0; mi < 4; mi++){
      #pragma unroll
      for (int r = 0; r < 4; r++){
        int row = aRow0 + mi*16 + quad*4 + r;
        #pragma unroll
        for (int nj = 0; nj < 4; nj++){
          int col = waveN*64 + nj*16 + cl;
          Hs[row*136 + col] = f2b(fmaxf(acc1[mi][nj][r] + b1v[nj], 0.0f));
        }
      }
    }
    // ---- FFN2 partial: out += hidden_chunk @ W2[kt*128.., :] ----
    for (int ks = 0; ks < 4; ks++){
      __syncthreads();   // Hs visible (first iter) / Bs WAR
      gll16(W2t + (size_t)lr*512 + kt*128 + ks*32 + kc*8, BsW);
      gll16(W2t + (size_t)(64 + lr)*512 + kt*128 + ks*32 + kc*8, BsW + 64*32);
      __syncthreads();
      bf16x8 af[4], bfr[4];
      #pragma unroll
      for (int mi = 0; mi < 4; mi++)
        af[mi] = *(const bf16x8*)(Hs + (aRow0 + mi*16 + cl)*136 + ks*32 + quad*8);
      #pragma unroll
      for (int nj = 0; nj < 4; nj++)
        bfr[nj] = *(const bf16x8*)(Bs + (waveN*64 + nj*16 + cl)*32 + quad*8);
      #pragma unroll
      for (int mi = 0; mi < 4; mi++)
        #pragma unroll
        for (int nj = 0; nj < 4; nj++)
          acc2[mi][nj] = __builtin_amdgcn_mfma_f32_16x16x32_bf16(af[mi], bfr[nj], acc2[mi][nj], 0,0,0);
    }
    __syncthreads();    // Hs WAR before next kt overwrites
  }
  // ---- epilogue: bias2 + residual-acc + fused LN. red aliases As. ----
  float (*red)[128][2] = (float (*)[128][2])(void*)As;
  int colW = waveN*64;
  float bv[4];
  #pragma unroll
  for (int nj = 0; nj < 4; nj++)
    bv[nj] = b2f(b2[colW + nj*16 + cl]);
  float hv[4][4][4];
  float psum[4][4], psq[4][4];
  #pragma unroll
  for (int mi = 0; mi < 4; mi++)
    #pragma unroll
    for (int r = 0; r < 4; r++){ psum[mi][r] = 0.f; psq[mi][r] = 0.f; }
  #pragma unroll
  for (int mi = 0; mi < 4; mi++){
    #pragma unroll
    for (int r = 0; r < 4; r++){
      int row = rowBase + aRow0 + mi*16 + quad*4 + r;
      #pragma unroll
      for (int nj = 0; nj < 4; nj++){
        int col = colW + nj*16 + cl;
        size_t idx = (size_t)row*D_ + col;
        float v = hout[idx] + acc2[mi][nj][r] + bv[nj];
        hout[idx] = v;
        hv[mi][nj][r] = v;
        psum[mi][r] += v; psq[mi][r] += v*v;
      }
    }
  }
  if (g){
    #pragma unroll
    for (int off = 1; off <= 8; off <<= 1)
      #pragma unroll
      for (int mi = 0; mi < 4; mi++)
        #pragma unroll
        for (int r = 0; r < 4; r++){
          psum[mi][r] += __shfl_xor(psum[mi][r], off, 64);
          psq[mi][r]  += __shfl_xor(psq[mi][r],  off, 64);
        }
    if (cl == 0){
      #pragma unroll
      for (int mi = 0; mi < 4; mi++)
        #pragma unroll
        for (int r = 0; r < 4; r++){
          int rl = aRow0 + mi*16 + quad*4 + r;
          red[waveN][rl][0] = psum[mi][r];
          red[waveN][rl][1] = psq[mi][r];
        }
    }
    __syncthreads();
    float gv[4], btv[4];
    #pragma unroll
    for (int nj = 0; nj < 4; nj++){
      int col = colW + nj*16 + cl;
      gv[nj] = b2f(g[col]); btv[nj] = b2f(bta[col]);
    }
    #pragma unroll
    for (int mi = 0; mi < 4; mi++){
      #pragma unroll
      for (int r = 0; r < 4; r++){
        int rl = aRow0 + mi*16 + quad*4 + r;
        float s = red[0][rl][0] + red[1][rl][0];
        float q = red[0][rl][1] + red[1][rl][1];
        float mean = s*(1.0f/128.0f);
        float var  = q*(1.0f/128.0f) - mean*mean;
        float rstd = rsqrtf(var + 1e-5f);
        int row = rowBase + rl;
        #pragma unroll
        for (int nj = 0; nj < 4; nj++){
          int col = colW + nj*16 + cl;
          xnb[(size_t)row*D_ + col] = f2b((hv[mi][nj][r]-mean)*rstd*gv[nj] + btv[nj]);
        }
      }
    }
  }
}

// ---- MFMA spatial attention (round-10 version) ----
__global__ __launch_bounds__(256,4) void sattn_k(const bf16* __restrict__ sQ,
    const bf16* __restrict__ sK, const bf16* __restrict__ sV,
    const float* __restrict__ maskg, bf16* __restrict__ ob){
  __shared__ __align__(16) _Float16 Vt[16*KVH];
  __shared__ __align__(16) _Float16 Ps[4*16*KVH];
  int tid = threadIdx.x;
  int bid = blockIdx.x;                // slab = (b*T+t)*H + hh
  int hh = bid & 7; int bt = bid >> 3; int t = bt % T_; int b = bt / T_;
  const bf16* Kslab = sK + (size_t)bid*SLAB;
  const bf16* Vslab = sV + (size_t)bid*SLAB;
  const bf16* Qslab = sQ + (size_t)bid*SLAB;
  for (int i = tid; i < 16*25; i += 256){ int d = i/25, c = 207 + i%25; Vt[d*KVH + c] = (_Float16)0.0f; }
  for (int i = tid; i < 64*24; i += 256){ int row = i/24, c = 208 + i%24; Ps[row*KVH + c] = (_Float16)0.0f; }
  for (int i = tid; i < SLAB; i += 256){
    int n = i >> 4, d = i & 15;
    Vt[d*KVH + n] = (_Float16)b2f(Vslab[i]);
  }
  __syncthreads();

  int lane = tid & 63, w = tid >> 6, quad = lane >> 4, cl = lane & 15;
  f16x8 ones8;
  #pragma unroll
  for (int j = 0; j < 8; j++) ones8[j] = (_Float16)1.0f;
  int nstripes = (w == 0) ? 4 : 3;
  for (int si = 0; si < nstripes; si++){
    int mi = w + si*4;
    bf16x8 aq = (bf16x8){0,0,0,0,0,0,0,0};
    {
      int n = mi*16 + cl; if (n > N_-1) n = N_-1;
      if (quad < 2) aq = *(const bf16x8*)(Qslab + n*16 + quad*8);
    }
    const float* mrow = maskg + ((size_t)mi*13)*256 + lane*4;
    f32x4 s[13];
    #pragma unroll
    for (int nj = 0; nj < 13; nj++){
      bf16x8 bk = (bf16x8){0,0,0,0,0,0,0,0};
      if (quad < 2){
        int nb = nj*16 + cl; if (nb > N_-1) nb = N_-1;
        bk = *(const bf16x8*)(Kslab + nb*16 + quad*8);
      }
      f32x4 c0 = *(const f32x4*)(mrow + nj*256);
      s[nj] = __builtin_amdgcn_mfma_f32_16x16x32_bf16(aq, bk, c0, 0,0,0);
    }
    int row0 = mi*16 + quad*4;
    _Float16* Pw = Ps + w*16*KVH;
    #pragma unroll
    for (int r = 0; r < 4; r++){
      _Float16* Pr = Pw + (quad*4 + r)*KVH;
      #pragma unroll
      for (int nj = 0; nj < 13; nj++)
        Pr[nj*16 + cl] = (_Float16)exp2f(s[nj][r]);
    }
    __threadfence_block();
    f32x4 o = {0.f,0.f,0.f,0.f};
    f32x4 osum = {0.f,0.f,0.f,0.f};
    #pragma unroll
    for (int kt = 0; kt < 7; kt++){
      f16x8 ap = *(const f16x8*)(Pw + cl*KVH + kt*32 + quad*8);
      f16x8 bv = *(const f16x8*)(Vt + cl*KVH + kt*32 + quad*8);
      o    = __builtin_amdgcn_mfma_f32_16x16x32_f16(ap, bv,    o,    0,0,0);
      osum = __builtin_amdgcn_mfma_f32_16x16x32_f16(ap, ones8, osum, 0,0,0);
    }
    #pragma unroll
    for (int r = 0; r < 4; r++){
      int rg = row0 + r;
      if (rg < N_)
        ob[((size_t)((b*N_ + rg)*T_ + t))*D_ + hh*HD_ + cl] = f2b(o[r]/osum[r]);
    }
    __threadfence_block();
  }
}

// ---- temporal attention ----
__global__ void tattn_k(const bf16* qkv, bf16* ob){
  int bid = blockIdx.x; int b = bid / N_, n = bid % N_;
  __shared__ float qs[T_*D_];
  __shared__ float ks[T_*D_];
  __shared__ float vs[T_*D_];
  size_t rowb = ((size_t)(b*N_+n)*T_)*384;
  const u32* src = (const u32*)(qkv + rowb);
  for (int idx = threadIdx.x; idx < T_*192; idx += 128){
    int tt = idx / 192, cw = idx - tt*192;
    u32 pr = src[tt*192 + cw];
    union { u32 u; bf16 b[2]; } cv; cv.u = pr;
    float v0 = b2f(cv.b[0]), v1 = b2f(cv.b[1]);
    int arr = cw >> 6, cp2 = (cw & 63)*2;
    float* dst = (arr == 0) ? qs : (arr == 1) ? ks : vs;
    dst[tt*128 + cp2] = v0; dst[tt*128 + cp2 + 1] = v1;
  }
  __syncthreads();
  int p = threadIdx.x;
  if (p < H_*T_){
    int hh = p / T_, t = p - hh*T_;
    float qreg[16];
    for (int d = 0; d < 16; d++) qreg[d] = qs[t*128 + hh*16 + d];
    float sc[12]; float mx = -3.4e38f;
    for (int s = 0; s < 12; s++){
      float a = 0.0f;
      for (int d = 0; d < 16; d++) a += qreg[d]*ks[s*128 + hh*16 + d];
      a = (s <= t) ? a*SCALE_ : -3.4e38f;
      sc[s] = a; mx = fmaxf(mx, a);
    }
    float ssum = 0.0f;
    for (int s = 0; s < 12; s++){
      float e = (s <= t) ? __expf(sc[s]-mx) : 0.0f;
      sc[s] = e; ssum += e;
    }
    float inv = 1.0f/ssum;
    size_t obase = ((size_t)(b*N_+n)*T_ + t)*D_ + hh*16;
    for (int d = 0; d < 16; d++){
      float acc = 0.0f;
      for (int s = 0; s < 12; s++) acc += sc[s]*vs[s*128 + hh*16 + d];
      ob[obase + d] = f2b(acc*inv);
    }
  }
}

// ---- VALU GEMM for small head GEMMs ----
__global__ void gemm_k(const bf16* A, int lda, const bf16* W, const bf16* bias,
                       void* outp, int ldo, int M, int Ncols, int K, int relu, int acc){
  __shared__ float Ast[16*68];
  __shared__ float Ws [16*68];
  int tx = threadIdx.x & 15, ty = threadIdx.x >> 4;
  int rowBase = blockIdx.y * 64, colBase = blockIdx.x * 64;
  float accr[4][4];
  for (int i = 0; i < 4; i++) for (int j = 0; j < 4; j++) accr[i][j] = 0.0f;
  for (int kk = 0; kk < K; kk += 16){
    int kq = threadIdx.x & 15, r0 = threadIdx.x >> 4;
    for (int it = 0; it < 4; it++){
      int r = r0 + it*16, row = rowBase + r;
      float v = 0.0f;
      if (row < M) v = b2f(A[(size_t)row*lda + kk + kq]);
      Ast[kq*68 + r] = v;
    }
    int c = threadIdx.x & 63, w0 = threadIdx.x >> 6;
    for (int it = 0; it < 4; it++){
      int kr = w0 + it*4;
      Ws[kr*68 + c] = b2f(W[(size_t)(kk+kr)*Ncols + colBase + c]);
    }
    __syncthreads();
    for (int k = 0; k < 16; k++){
      float av[4], wv[4];
      for (int i = 0; i < 4; i++) av[i] = Ast[k*68 + ty*4 + i];
      for (int j = 0; j < 4; j++) wv[j] = Ws[k*68 + tx*4 + j];
      for (int i = 0; i < 4; i++)
        for (int j = 0; j < 4; j++) accr[i][j] += av[i]*wv[j];
    }
    __syncthreads();
  }
  for (int i = 0; i < 4; i++){
    int row = rowBase + ty*4 + i;
    if (row >= M) continue;
    for (int j = 0; j < 4; j++){
      int col = colBase + tx*4 + j;
      float v = accr[i][j];
      if (bias) v += b2f(bias[col]);
      if (relu) v = fmaxf(v, 0.0f);
      if (acc) ((float*)outp)[(size_t)row*ldo + col] += v;
      else     ((bf16*)outp)[(size_t)row*ldo + col] = f2b(v);
    }
  }
}

__global__ void gather_k(const float* h, bf16* hlb){
  int i = blockIdx.x*256 + threadIdx.x;
  if (i >= ROWS2*D_) return;
  int r = i >> 7, d = i & 127;
  hlb[i] = f2b(h[((size_t)r*T_ + (T_-1))*D_ + d]);
}

__global__ void head3_k(const bf16* z2, const bf16* P3, const bf16* Pb3,
                        void* out, int out_n, const int* flag){
  int i = blockIdx.x*256 + threadIdx.x;
  if (i >= out_n) return;
  int r = i / PL_, j = i - r*PL_;
  float acc = b2f(Pb3[j]);
  for (int d = 0; d < 128; d++) acc += b2f(z2[(size_t)r*128 + d]) * b2f(P3[d*PL_ + j]);
  if (*flag) ((bf16*)out)[i] = f2b(acc);
  else       ((float*)out)[i] = acc;
}

extern "C" void kernel_launch(void* const* d_in, const int* in_sizes, int n_in,
                              void* d_out, int out_size, void* d_ws, size_t ws_size,
                              hipStream_t stream){
  size_t HB = (size_t)TOK*D_*4;
  size_t XB = (size_t)TOK*D_*2;
  size_t RB = (size_t)TOK*D_*8;
  float* h    = (float*)d_ws;
  bf16*  xnb  = (bf16*)((char*)d_ws + HB);
  bf16*  reg_ = (bf16*)((char*)d_ws + HB + XB);
  bf16*  cvt  = (bf16*)((char*)d_ws + HB + XB + RB);
  bf16*  wsb  = (bf16*)d_ws;
  const int FIDX[34] = {0,2,3,4,5,6,7,8,9,10,11,12,13,14,15,16,17,18,19,20,
                        21,22,23,24,25,26,27,28,29,30,31,32,33,34};
  bf16* cp[34];
  size_t off = 0;
  for (int i = 0; i < 34; i++){ cp[i] = cvt + off; off += (size_t)in_sizes[FIDX[i]]; }
  char* tail   = (char*)d_ws + HB + XB + RB + ((off*2 + 255) & ~(size_t)255);
  float* maskg = (float*)tail;
  bf16* qkvw   = (bf16*)(tail + (size_t)MSK_N*4);
  int*  flag   = (int*)(tail + (size_t)MSK_N*4 + (size_t)L_*384*128*2);

  const bf16 *x_c=cp[0], *Wi_c=cp[1], *bi_c=cp[2],
             *Wo_t=cp[6], *bo_c=cp[7], *sW1_t=cp[8], *sB1_c=cp[9], *sW2_t=cp[10], *sB2_c=cp[11],
             *sg1_c=cp[12], *sh1_c=cp[13], *sg2_c=cp[14], *sh2_c=cp[15], *Win_t=cp[16], *Bin_c=cp[17],
             *Wout_t=cp[18], *Bout_c=cp[19], *tW1_t=cp[20], *tB1_c=cp[21], *tW2_t=cp[22], *tB2_c=cp[23],
             *tg1_c=cp[24], *th1_c=cp[25], *tg2_c=cp[26], *th2_c=cp[27], *P1_c=cp[28], *Pb1_c=cp[29],
             *P2_c=cp[30], *Pb2_c=cp[31], *P3_c=cp[32], *Pb3_c=cp[33];
  const int* adj = (const int*)d_in[1];

  bf16* sQ   = reg_;
  bf16* sK   = reg_ + (size_t)TOK*128;
  bf16* sV   = reg_ + (size_t)2*TOK*128;
  bf16* ob   = reg_ + (size_t)3*TOK*128;
  bf16* qkvb = reg_;

  detect_k<<<1, 256, 0, stream>>>(d_in[0], flag);

  {
    const int FLAT[24] = {0,1,2,7,9,11,12,13,14,15,17,19,21,23,24,25,26,27,28,29,30,31,32,33};
    FlatArgs fa; int c = 0;
    for (int ii = 0; ii < 24; ii++){
      int ci = FLAT[ii];
      fa.src[ii] = d_in[FIDX[ci]];
      fa.dst[ii] = (long long)(cp[ci] - wsb);
      fa.cum[ii] = c;
      c += in_sizes[FIDX[ci]];
    }
    fa.cum[24] = c;
    cvt_flat_k<<<(c+255)/256, 256, 0, stream>>>(fa, wsb, flag, c);
  }
  {
    TArgs ta; int c = 0;
    const void* srcs[10] = {d_in[4], d_in[5], d_in[6], d_in[7], d_in[9], d_in[11],
                            d_in[17], d_in[19], d_in[21], d_in[23]};
    bf16* dsts[10] = {qkvw, qkvw, qkvw, cp[6], cp[8], cp[10], cp[16], cp[18], cp[20], cp[22]};
    int Ks_[10]   = {128,128,128, 128, 128, 512, 128, 128, 128, 512};
    int Ncs[10]   = {128,128,128, 128, 512, 128, 384, 128, 512, 128};
    int Lst[10]   = {384*128,384*128,384*128, 128*128, 128*512, 512*128, 128*384, 128*128, 128*512, 512*128};
    int ros[10]   = {0,128,256, 0,0,0, 0,0,0, 0};
    for (int j = 0; j < 10; j++){
      ta.src[j] = srcs[j];
      ta.dst[j] = (long long)(dsts[j] - wsb);
      ta.K[j] = Ks_[j]; ta.Nc[j] = Ncs[j]; ta.Lstr[j] = Lst[j]; ta.ro[j] = ros[j];
      ta.scale[j] = (j == 0) ? SCALE_*LOG2E_ : 1.0f;
      ta.cum[j] = c;
      c += L_*Ks_[j]*Ncs[j];
    }
    ta.cum[10] = c;
    cvt_t_k<<<(c+255)/256, 256, 0, stream>>>(ta, wsb, flag, c);
  }
  maskc_k<<<(MSK_N+255)/256, 256, 0, stream>>>(adj, maskg);
  embed_ln_k<<<TOK/4, 256, 0, stream>>>(x_c, Wi_c, bi_c, sg1_c, sh1_c, h, xnb);

  const dim3 gP  (1, TOK/128);
  const dim3 gQKV(3, TOK/128);

  for (int l = 0; l < L_; l++){
    // spatial attention
    mgemm_qkvT_k<<<gQKV, 256, 0, stream>>>(xnb, qkvw + (size_t)l*384*128, sQ, sK, sV);
    sattn_k<<<B_*T_*H_, 256, 0, stream>>>(sQ, sK, sV, maskg, ob);
    mgemm_ln_k<<<gP, 256, 0, stream>>>(ob, Wo_t + (size_t)l*D_*D_, bo_c + l*D_, h, D_,
                                       sg2_c + l*D_, sh2_c + l*D_, xnb);
    // fused FFN 1 (-> LN tg1)
    mffn_ln_k<<<TOK/128, 256, 0, stream>>>(xnb, sW1_t + (size_t)l*D_*FF_, sB1_c + l*FF_,
                                           sW2_t + (size_t)l*FF_*D_, sB2_c + l*D_, h,
                                           tg1_c + l*D_, th1_c + l*D_, xnb);
    // temporal attention
    mgemm_k<<<gQKV, 256, 0, stream>>>(xnb, Win_t + (size_t)l*D_*384, Bin_c + l*384, qkvb, 384, D_, 0);
    tattn_k<<<B_*N_, 128, 0, stream>>>(qkvb, ob);
    mgemm_ln_k<<<gP, 256, 0, stream>>>(ob, Wout_t + (size_t)l*D_*D_, Bout_c + l*D_, h, D_,
                                       tg2_c + l*D_, th2_c + l*D_, xnb);
    // fused FFN 2 (-> LN next sg1 or none)
    const bf16* gnext = (l < L_-1) ? (sg1_c + (l+1)*D_) : nullptr;
    const bf16* bnext = (l < L_-1) ? (sh1_c + (l+1)*D_) : nullptr;
    mffn_ln_k<<<TOK/128, 256, 0, stream>>>(xnb, tW1_t + (size_t)l*D_*FF_, tB1_c + l*FF_,
                                           tW2_t + (size_t)l*FF_*D_, tB2_c + l*D_, h,
                                           gnext, bnext, xnb);
  }

  // head
  bf16* hlb = reg_;
  bf16* z1  = reg_ + (size_t)ROWS2*128;
  bf16* z2  = z1   + (size_t)ROWS2*256;
  gather_k<<<(ROWS2*D_)/256, 256, 0, stream>>>(h, hlb);
  gemm_k<<<dim3(256/64, (ROWS2+63)/64), 256, 0, stream>>>(hlb, 128, P1_c, Pb1_c, z1, 256, ROWS2, 256, 128, 1, 0);
  gemm_k<<<dim3(128/64, (ROWS2+63)/64), 256, 0, stream>>>(z1, 256, P2_c, Pb2_c, z2, 128, ROWS2, 128, 256, 1, 0);
  head3_k<<<(out_size+255)/256, 256, 0, stream>>>(z2, P3_c, Pb3_c, d_out, out_size, flag);
}

// Round 14
// 1569.628 us; speedup vs baseline: 1.1685x; 1.1190x over previous
//
#include <hip/hip_runtime.h>
#include <hip/hip_bf16.h>

#define B_   32
#define N_   207
#define T_   12
#define D_   128
#define H_   8
#define HD_  16
#define L_   4
#define FF_  512
#define PL_  12
#define TOK  (B_*N_*T_)      // 79488 = 621*128
#define ROWS2 (B_*N_)        // 6624
#define SCALE_ 0.25f
#define LOG2E_ 1.4426950408889634f
#define NEG2_ -1.4426950409e9f   // -1e9 in log2 domain
#define KVH  232             // Vt/P row stride (fp16)
#define SLAB 3312            // 207*16 elements per (b,t,h) slab
#define MSK_N (13*13*256)    // mask elements in C-frag layout

typedef __hip_bfloat16 bf16;
typedef unsigned int u32;
typedef __attribute__((ext_vector_type(4))) unsigned int u32x4;
typedef __attribute__((ext_vector_type(8))) short bf16x8;     // 8 bf16 (MFMA A/B frag)
typedef __attribute__((ext_vector_type(8))) _Float16 f16x8;   // 8 fp16 (MFMA A/B frag)
typedef __attribute__((ext_vector_type(4))) float f32x4;      // MFMA C/D frag

__device__ __forceinline__ float b2f(bf16 x){ return __bfloat162float(x); }
__device__ __forceinline__ bf16  f2b(float x){ return __float2bfloat16(x); }

// async global->LDS 16B per lane (dest must be wave-uniform base + lane*16)
__device__ __forceinline__ void gll16(const bf16* g, bf16* l){
  __builtin_amdgcn_global_load_lds((const __attribute__((address_space(1))) void*)g,
                                   (__attribute__((address_space(3))) void*)l, 16, 0, 0);
}

// ---- dtype detection ----
__global__ void detect_k(const void* x, int* flag){
  __shared__ int cnt[256];
  const unsigned short* u = (const unsigned short*)x;
  int ok = 0;
  for (int i = threadIdx.x; i < 4096; i += 256){
    unsigned int bits = ((unsigned int)u[i]) << 16;
    float f = __uint_as_float(bits);
    float a = fabsf(f);
    if (f == 0.0f || (a > 1e-4f && a < 64.0f)) ok++;
  }
  cnt[threadIdx.x] = ok;
  __syncthreads();
  for (int s = 128; s > 0; s >>= 1){
    if (threadIdx.x < s) cnt[threadIdx.x] += cnt[threadIdx.x + s];
    __syncthreads();
  }
  if (threadIdx.x == 0) *flag = (cnt[0] > 3686) ? 1 : 0;
}

// ---- batched flat convert ----
struct FlatArgs {
  const void* src[24];
  long long dst[24];
  int cum[25];
};
__global__ void cvt_flat_k(FlatArgs a, bf16* base, const int* flag, int total){
  int i = blockIdx.x*256 + threadIdx.x;
  if (i >= total) return;
  int j = 0;
  while (i >= a.cum[j+1]) j++;
  int loc = i - a.cum[j];
  float v = (*flag) ? b2f(((const bf16*)a.src[j])[loc]) : ((const float*)a.src[j])[loc];
  base[a.dst[j] + loc] = f2b(v);
}

// ---- batched transpose convert (with per-segment scale) ----
struct TArgs {
  const void* src[10];
  long long dst[10];
  int K[10], Nc[10], Lstr[10], ro[10];
  float scale[10];
  int cum[11];
};
__global__ void cvt_t_k(TArgs a, bf16* base, const int* flag, int total){
  int i = blockIdx.x*256 + threadIdx.x;
  if (i >= total) return;
  int j = 0;
  while (i >= a.cum[j+1]) j++;
  int loc = i - a.cum[j];
  int KN = a.K[j]*a.Nc[j];
  int l = loc / KN; int rm = loc - l*KN; int k = rm / a.Nc[j]; int n = rm - k*a.Nc[j];
  float v = (*flag) ? b2f(((const bf16*)a.src[j])[loc]) : ((const float*)a.src[j])[loc];
  base[a.dst[j] + (long long)l*a.Lstr[j] + (long long)(a.ro[j]+n)*a.K[j] + k] = f2b(v*a.scale[j]);
}

// ---- additive mask in MFMA C-fragment layout (log2 domain) ----
__global__ void maskc_k(const int* adj, float* maskg){
  int i = blockIdx.x*256 + threadIdx.x;
  if (i >= MSK_N) return;
  int cell = i >> 8;             // mi*13+nj
  int mi = cell / 13, nj = cell - mi*13;
  int rem = i & 255;
  int lane = rem >> 2, r = rem & 3;
  int quad = lane >> 4, cl = lane & 15;
  int row = mi*16 + quad*4 + r; if (row > 206) row = 206;
  int col = nj*16 + cl;
  float v;
  if (col > 206) v = -1e30f;
  else v = adj[row*N_ + col] ? 0.0f : NEG2_;
  maskg[i] = v;
}

// ---- embed + fused LN (layer 0) ----
__global__ void embed_ln_k(const bf16* x, const bf16* Wi, const bf16* bi,
                           const bf16* g, const bf16* bta, float* h, bf16* xnb){
  int wave = threadIdx.x >> 6, lane = threadIdx.x & 63;
  int tok = blockIdx.x*4 + wave;
  if (tok >= TOK) return;
  float xv = b2f(x[tok]);
  float v0 = xv*b2f(Wi[lane])    + b2f(bi[lane]);
  float v1 = xv*b2f(Wi[lane+64]) + b2f(bi[lane+64]);
  float* hp = h + (size_t)tok*D_;
  hp[lane] = v0; hp[lane+64] = v1;
  float s = v0 + v1;
  for (int off = 32; off >= 1; off >>= 1) s += __shfl_xor(s, off, 64);
  float m = s * (1.0f/128.0f);
  float d0 = v0 - m, d1 = v1 - m;
  float vv = d0*d0 + d1*d1;
  for (int off = 32; off >= 1; off >>= 1) vv += __shfl_xor(vv, off, 64);
  float r = rsqrtf(vv*(1.0f/128.0f) + 1e-5f);
  bf16* op = xnb + (size_t)tok*D_;
  op[lane]    = f2b(d0*r*b2f(g[lane])    + b2f(bta[lane]));
  op[lane+64] = f2b(d1*r*b2f(g[lane+64]) + b2f(bta[lane+64]));
}

// ---- MFMA GEMM (non-acc), global_load_lds staging ----
__global__ __launch_bounds__(256) void mgemm_k(const bf16* __restrict__ A,
    const bf16* __restrict__ Wt, const bf16* __restrict__ bias,
    bf16* __restrict__ outp, int ldo, int Ktot, int relu){
  __shared__ __align__(16) bf16 As[128*32];
  __shared__ __align__(16) bf16 Bs[128*32];
  int tid = threadIdx.x;
  int rowBase = blockIdx.y * 128, colBase = blockIdx.x * 128;
  int w = tid >> 6, lane = tid & 63, quad = lane >> 4, cl = lane & 15;
  int waveM = w >> 1, waveN = w & 1;
  f32x4 accr[4][4];
  #pragma unroll
  for (int i = 0; i < 4; i++)
    #pragma unroll
    for (int j = 0; j < 4; j++) accr[i][j] = (f32x4){0.f,0.f,0.f,0.f};
  int lr = tid >> 2, kc = tid & 3;
  const bf16* Ap = A  + (size_t)(rowBase + lr)*Ktot + kc*8;
  const bf16* Bp = Wt + (size_t)(colBase + lr)*Ktot + kc*8;
  bf16* AsW = As + tid*8;
  bf16* BsW = Bs + tid*8;
  for (int kk = 0; kk < Ktot; kk += 32){
    __syncthreads();
    gll16(Ap + kk, AsW);
    gll16(Ap + (size_t)64*Ktot + kk, AsW + 64*32);
    gll16(Bp + kk, BsW);
    gll16(Bp + (size_t)64*Ktot + kk, BsW + 64*32);
    __syncthreads();
    bf16x8 af[4], bfr[4];
    #pragma unroll
    for (int mi = 0; mi < 4; mi++)
      af[mi] = *(const bf16x8*)(As + (waveM*64 + mi*16 + cl)*32 + quad*8);
    #pragma unroll
    for (int nj = 0; nj < 4; nj++)
      bfr[nj] = *(const bf16x8*)(Bs + (waveN*64 + nj*16 + cl)*32 + quad*8);
    #pragma unroll
    for (int mi = 0; mi < 4; mi++)
      #pragma unroll
      for (int nj = 0; nj < 4; nj++)
        accr[mi][nj] = __builtin_amdgcn_mfma_f32_16x16x32_bf16(af[mi], bfr[nj], accr[mi][nj], 0,0,0);
  }
  float bv[4];
  #pragma unroll
  for (int nj = 0; nj < 4; nj++)
    bv[nj] = bias ? b2f(bias[colBase + waveN*64 + nj*16 + cl]) : 0.0f;
  #pragma unroll
  for (int mi = 0; mi < 4; mi++){
    int row0 = rowBase + waveM*64 + mi*16 + quad*4;
    #pragma unroll
    for (int nj = 0; nj < 4; nj++){
      int col = colBase + waveN*64 + nj*16 + cl;
      #pragma unroll
      for (int r = 0; r < 4; r++){
        float v = accr[mi][nj][r] + bv[nj];
        if (relu) v = fmaxf(v, 0.0f);
        outp[(size_t)(row0+r)*ldo + col] = f2b(v);
      }
    }
  }
}

// ---- MFMA GEMM writing spatial q/k/v in [slab=(b,t,h)][n][16] layout ----
__global__ __launch_bounds__(256) void mgemm_qkvT_k(const bf16* __restrict__ A,
    const bf16* __restrict__ Wt, bf16* __restrict__ sQ,
    bf16* __restrict__ sK, bf16* __restrict__ sV){
  __shared__ __align__(16) bf16 As[128*32];
  __shared__ __align__(16) bf16 Bs[128*32];
  const int Ktot = 128;
  int tid = threadIdx.x;
  int rowBase = blockIdx.y * 128, colBase = blockIdx.x * 128;
  int w = tid >> 6, lane = tid & 63, quad = lane >> 4, cl = lane & 15;
  int waveM = w >> 1, waveN = w & 1;
  f32x4 accr[4][4];
  #pragma unroll
  for (int i = 0; i < 4; i++)
    #pragma unroll
    for (int j = 0; j < 4; j++) accr[i][j] = (f32x4){0.f,0.f,0.f,0.f};
  int lr = tid >> 2, kc = tid & 3;
  const bf16* Ap = A  + (size_t)(rowBase + lr)*Ktot + kc*8;
  const bf16* Bp = Wt + (size_t)(colBase + lr)*Ktot + kc*8;
  bf16* AsW = As + tid*8;
  bf16* BsW = Bs + tid*8;
  for (int kk = 0; kk < Ktot; kk += 32){
    __syncthreads();
    gll16(Ap + kk, AsW);
    gll16(Ap + (size_t)64*Ktot + kk, AsW + 64*32);
    gll16(Bp + kk, BsW);
    gll16(Bp + (size_t)64*Ktot + kk, BsW + 64*32);
    __syncthreads();
    bf16x8 af[4], bfr[4];
    #pragma unroll
    for (int mi = 0; mi < 4; mi++)
      af[mi] = *(const bf16x8*)(As + (waveM*64 + mi*16 + cl)*32 + quad*8);
    #pragma unroll
    for (int nj = 0; nj < 4; nj++)
      bfr[nj] = *(const bf16x8*)(Bs + (waveN*64 + nj*16 + cl)*32 + quad*8);
    #pragma unroll
    for (int mi = 0; mi < 4; mi++)
      #pragma unroll
      for (int nj = 0; nj < 4; nj++)
        accr[mi][nj] = __builtin_amdgcn_mfma_f32_16x16x32_bf16(af[mi], bfr[nj], accr[mi][nj], 0,0,0);
  }
  #pragma unroll
  for (int mi = 0; mi < 4; mi++){
    #pragma unroll
    for (int r = 0; r < 4; r++){
      int tok = rowBase + waveM*64 + mi*16 + quad*4 + r;
      int bn = tok / T_; int t = tok - bn*T_;
      int b = bn / N_;  int n = bn - b*N_;
      size_t base = ((size_t)(b*T_ + t)*H_)*SLAB + n*16 + cl;
      #pragma unroll
      for (int nj = 0; nj < 4; nj++){
        int col = colBase + waveN*64 + nj*16;
        int part = col >> 7, hh = (col >> 4) & 7;
        bf16* dst = (part == 0) ? sQ : (part == 1) ? sK : sV;
        dst[base + (size_t)hh*SLAB] = f2b(accr[mi][nj][r]);
      }
    }
  }
}

// ---- MFMA GEMM + residual-acc + fused LayerNorm (N=128, grid.x=1) ----
__global__ __launch_bounds__(256) void mgemm_ln_k(const bf16* __restrict__ A,
    const bf16* __restrict__ Wt, const bf16* __restrict__ bias,
    float* __restrict__ hout, int Ktot,
    const bf16* __restrict__ g, const bf16* __restrict__ bta,
    bf16* __restrict__ xnb){
  __shared__ __align__(16) bf16 As[128*32];
  __shared__ __align__(16) bf16 Bs[128*32];
  __shared__ float red[2][128][2];
  int tid = threadIdx.x;
  int rowBase = blockIdx.y * 128;
  int w = tid >> 6, lane = tid & 63, quad = lane >> 4, cl = lane & 15;
  int waveM = w >> 1, waveN = w & 1;
  f32x4 accr[4][4];
  #pragma unroll
  for (int i = 0; i < 4; i++)
    #pragma unroll
    for (int j = 0; j < 4; j++) accr[i][j] = (f32x4){0.f,0.f,0.f,0.f};
  int lr = tid >> 2, kc = tid & 3;
  const bf16* Ap = A  + (size_t)(rowBase + lr)*Ktot + kc*8;
  const bf16* Bp = Wt + (size_t)lr*Ktot + kc*8;
  bf16* AsW = As + tid*8;
  bf16* BsW = Bs + tid*8;
  for (int kk = 0; kk < Ktot; kk += 32){
    __syncthreads();
    gll16(Ap + kk, AsW);
    gll16(Ap + (size_t)64*Ktot + kk, AsW + 64*32);
    gll16(Bp + kk, BsW);
    gll16(Bp + (size_t)64*Ktot + kk, BsW + 64*32);
    __syncthreads();
    bf16x8 af[4], bfr[4];
    #pragma unroll
    for (int mi = 0; mi < 4; mi++)
      af[mi] = *(const bf16x8*)(As + (waveM*64 + mi*16 + cl)*32 + quad*8);
    #pragma unroll
    for (int nj = 0; nj < 4; nj++)
      bfr[nj] = *(const bf16x8*)(Bs + (waveN*64 + nj*16 + cl)*32 + quad*8);
    #pragma unroll
    for (int mi = 0; mi < 4; mi++)
      #pragma unroll
      for (int nj = 0; nj < 4; nj++)
        accr[mi][nj] = __builtin_amdgcn_mfma_f32_16x16x32_bf16(af[mi], bfr[nj], accr[mi][nj], 0,0,0);
  }
  int colW = waveN*64;
  float bv[4];
  #pragma unroll
  for (int nj = 0; nj < 4; nj++)
    bv[nj] = bias ? b2f(bias[colW + nj*16 + cl]) : 0.0f;
  float hv[4][4][4];
  float psum[4][4], psq[4][4];
  #pragma unroll
  for (int mi = 0; mi < 4; mi++)
    #pragma unroll
    for (int r = 0; r < 4; r++){ psum[mi][r] = 0.f; psq[mi][r] = 0.f; }
  #pragma unroll
  for (int mi = 0; mi < 4; mi++){
    #pragma unroll
    for (int r = 0; r < 4; r++){
      int row = rowBase + waveM*64 + mi*16 + quad*4 + r;
      #pragma unroll
      for (int nj = 0; nj < 4; nj++){
        int col = colW + nj*16 + cl;
        size_t idx = (size_t)row*D_ + col;
        float v = hout[idx] + accr[mi][nj][r] + bv[nj];
        hout[idx] = v;
        hv[mi][nj][r] = v;
        psum[mi][r] += v; psq[mi][r] += v*v;
      }
    }
  }
  if (g){
    #pragma unroll
    for (int off = 1; off <= 8; off <<= 1)
      #pragma unroll
      for (int mi = 0; mi < 4; mi++)
        #pragma unroll
        for (int r = 0; r < 4; r++){
          psum[mi][r] += __shfl_xor(psum[mi][r], off, 64);
          psq[mi][r]  += __shfl_xor(psq[mi][r],  off, 64);
        }
    if (cl == 0){
      #pragma unroll
      for (int mi = 0; mi < 4; mi++)
        #pragma unroll
        for (int r = 0; r < 4; r++){
          int rl = waveM*64 + mi*16 + quad*4 + r;
          red[waveN][rl][0] = psum[mi][r];
          red[waveN][rl][1] = psq[mi][r];
        }
    }
    __syncthreads();
    float gv[4], btv[4];
    #pragma unroll
    for (int nj = 0; nj < 4; nj++){
      int col = colW + nj*16 + cl;
      gv[nj] = b2f(g[col]); btv[nj] = b2f(bta[col]);
    }
    #pragma unroll
    for (int mi = 0; mi < 4; mi++){
      #pragma unroll
      for (int r = 0; r < 4; r++){
        int rl = waveM*64 + mi*16 + quad*4 + r;
        float s = red[0][rl][0] + red[1][rl][0];
        float q = red[0][rl][1] + red[1][rl][1];
        float mean = s*(1.0f/128.0f);
        float var  = q*(1.0f/128.0f) - mean*mean;
        float rstd = rsqrtf(var + 1e-5f);
        int row = rowBase + rl;
        #pragma unroll
        for (int nj = 0; nj < 4; nj++){
          int col = colW + nj*16 + cl;
          xnb[(size_t)row*D_ + col] = f2b((hv[mi][nj][r]-mean)*rstd*gv[nj] + btv[nj]);
        }
      }
    }
  }
}

// ---- fused FFN: h += relu(xn@W1+b1)@W2 + b2; xnb = LN(h) ----
// Round-10 version: A staged once in LDS, hidden chunk LDS-resident.
__global__ __launch_bounds__(256,2) void mffn_ln_k(const bf16* __restrict__ A,
    const bf16* __restrict__ W1t, const bf16* __restrict__ b1,
    const bf16* __restrict__ W2t, const bf16* __restrict__ b2,
    float* __restrict__ hout,
    const bf16* __restrict__ g, const bf16* __restrict__ bta,
    bf16* __restrict__ xnb){
  __shared__ __align__(16) bf16 As[128*136];
  __shared__ __align__(16) bf16 Hs[128*136];
  __shared__ __align__(16) bf16 Bs[128*32];
  __shared__ float red[2][128][2];
  int tid = threadIdx.x;
  int rowBase = blockIdx.x * 128;
  int w = tid >> 6, lane = tid & 63, quad = lane >> 4, cl = lane & 15;
  int waveM = w >> 1, waveN = w & 1;
  for (int i = tid; i < 128*16; i += 256){
    int row = i >> 4, ch = i & 15;
    u32x4 v = *(const u32x4*)(A + (size_t)(rowBase + row)*128 + ch*8);
    *(u32x4*)(As + row*136 + ch*8) = v;
  }
  f32x4 acc2[4][4];
  #pragma unroll
  for (int i = 0; i < 4; i++)
    #pragma unroll
    for (int j = 0; j < 4; j++) acc2[i][j] = (f32x4){0.f,0.f,0.f,0.f};
  int lr = tid >> 2, kc = tid & 3;
  bf16* BsW = Bs + tid*8;
  int aRow0 = waveM*64;
  for (int kt = 0; kt < 4; kt++){
    f32x4 acc1[4][4];
    #pragma unroll
    for (int i = 0; i < 4; i++)
      #pragma unroll
      for (int j = 0; j < 4; j++) acc1[i][j] = (f32x4){0.f,0.f,0.f,0.f};
    for (int ks = 0; ks < 4; ks++){
      __syncthreads();
      gll16(W1t + (size_t)(kt*128 + lr)*128 + ks*32 + kc*8, BsW);
      gll16(W1t + (size_t)(kt*128 + 64 + lr)*128 + ks*32 + kc*8, BsW + 64*32);
      __syncthreads();
      bf16x8 af[4], bfr[4];
      #pragma unroll
      for (int mi = 0; mi < 4; mi++)
        af[mi] = *(const bf16x8*)(As + (aRow0 + mi*16 + cl)*136 + ks*32 + quad*8);
      #pragma unroll
      for (int nj = 0; nj < 4; nj++)
        bfr[nj] = *(const bf16x8*)(Bs + (waveN*64 + nj*16 + cl)*32 + quad*8);
      #pragma unroll
      for (int mi = 0; mi < 4; mi++)
        #pragma unroll
        for (int nj = 0; nj < 4; nj++)
          acc1[mi][nj] = __builtin_amdgcn_mfma_f32_16x16x32_bf16(af[mi], bfr[nj], acc1[mi][nj], 0,0,0);
    }
    float b1v[4];
    #pragma unroll
    for (int nj = 0; nj < 4; nj++)
      b1v[nj] = b2f(b1[kt*128 + waveN*64 + nj*16 + cl]);
    #pragma unroll
    for (int mi = 0; mi < 4; mi++){
      #pragma unroll
      for (int r = 0; r < 4; r++){
        int row = aRow0 + mi*16 + quad*4 + r;
        #pragma unroll
        for (int nj = 0; nj < 4; nj++){
          int col = waveN*64 + nj*16 + cl;
          Hs[row*136 + col] = f2b(fmaxf(acc1[mi][nj][r] + b1v[nj], 0.0f));
        }
      }
    }
    for (int ks = 0; ks < 4; ks++){
      __syncthreads();
      gll16(W2t + (size_t)lr*512 + kt*128 + ks*32 + kc*8, BsW);
      gll16(W2t + (size_t)(64 + lr)*512 + kt*128 + ks*32 + kc*8, BsW + 64*32);
      __syncthreads();
      bf16x8 af[4], bfr[4];
      #pragma unroll
      for (int mi = 0; mi < 4; mi++)
        af[mi] = *(const bf16x8*)(Hs + (aRow0 + mi*16 + cl)*136 + ks*32 + quad*8);
      #pragma unroll
      for (int nj = 0; nj < 4; nj++)
        bfr[nj] = *(const bf16x8*)(Bs + (waveN*64 + nj*16 + cl)*32 + quad*8);
      #pragma unroll
      for (int mi = 0; mi < 4; mi++)
        #pragma unroll
        for (int nj = 0; nj < 4; nj++)
          acc2[mi][nj] = __builtin_amdgcn_mfma_f32_16x16x32_bf16(af[mi], bfr[nj], acc2[mi][nj], 0,0,0);
    }
    __syncthreads();
  }
  int colW = waveN*64;
  float bv[4];
  #pragma unroll
  for (int nj = 0; nj < 4; nj++)
    bv[nj] = b2f(b2[colW + nj*16 + cl]);
  float hv[4][4][4];
  float psum[4][4], psq[4][4];
  #pragma unroll
  for (int mi = 0; mi < 4; mi++)
    #pragma unroll
    for (int r = 0; r < 4; r++){ psum[mi][r] = 0.f; psq[mi][r] = 0.f; }
  #pragma unroll
  for (int mi = 0; mi < 4; mi++){
    #pragma unroll
    for (int r = 0; r < 4; r++){
      int row = rowBase + aRow0 + mi*16 + quad*4 + r;
      #pragma unroll
      for (int nj = 0; nj < 4; nj++){
        int col = colW + nj*16 + cl;
        size_t idx = (size_t)row*D_ + col;
        float v = hout[idx] + acc2[mi][nj][r] + bv[nj];
        hout[idx] = v;
        hv[mi][nj][r] = v;
        psum[mi][r] += v; psq[mi][r] += v*v;
      }
    }
  }
  if (g){
    #pragma unroll
    for (int off = 1; off <= 8; off <<= 1)
      #pragma unroll
      for (int mi = 0; mi < 4; mi++)
        #pragma unroll
        for (int r = 0; r < 4; r++){
          psum[mi][r] += __shfl_xor(psum[mi][r], off, 64);
          psq[mi][r]  += __shfl_xor(psq[mi][r],  off, 64);
        }
    if (cl == 0){
      #pragma unroll
      for (int mi = 0; mi < 4; mi++)
        #pragma unroll
        for (int r = 0; r < 4; r++){
          int rl = aRow0 + mi*16 + quad*4 + r;
          red[waveN][rl][0] = psum[mi][r];
          red[waveN][rl][1] = psq[mi][r];
        }
    }
    __syncthreads();
    float gv[4], btv[4];
    #pragma unroll
    for (int nj = 0; nj < 4; nj++){
      int col = colW + nj*16 + cl;
      gv[nj] = b2f(g[col]); btv[nj] = b2f(bta[col]);
    }
    #pragma unroll
    for (int mi = 0; mi < 4; mi++){
      #pragma unroll
      for (int r = 0; r < 4; r++){
        int rl = aRow0 + mi*16 + quad*4 + r;
        float s = red[0][rl][0] + red[1][rl][0];
        float q = red[0][rl][1] + red[1][rl][1];
        float mean = s*(1.0f/128.0f);
        float var  = q*(1.0f/128.0f) - mean*mean;
        float rstd = rsqrtf(var + 1e-5f);
        int row = rowBase + rl;
        #pragma unroll
        for (int nj = 0; nj < 4; nj++){
          int col = colW + nj*16 + cl;
          xnb[(size_t)row*D_ + col] = f2b((hv[mi][nj][r]-mean)*rstd*gv[nj] + btv[nj]);
        }
      }
    }
  }
}

// ---- MFMA spatial attention: K from global (L1-resident), MFMA row-sum,
// exp2 softmax (log2e folded into Wq/mask). LDS 37KB -> 4 blocks/CU. ----
__global__ __launch_bounds__(256,4) void sattn_k(const bf16* __restrict__ sQ,
    const bf16* __restrict__ sK, const bf16* __restrict__ sV,
    const float* __restrict__ maskg, bf16* __restrict__ ob){
  __shared__ __align__(16) _Float16 Vt[16*KVH];     // 7424 B
  __shared__ __align__(16) _Float16 Ps[4*16*KVH];   // 29696 B
  int tid = threadIdx.x;
  int bid = blockIdx.x;                // slab = (b*T+t)*H + hh
  int hh = bid & 7; int bt = bid >> 3; int t = bt % T_; int b = bt / T_;
  const bf16* Kslab = sK + (size_t)bid*SLAB;
  const bf16* Vslab = sV + (size_t)bid*SLAB;
  const bf16* Qslab = sQ + (size_t)bid*SLAB;
  for (int i = tid; i < 16*25; i += 256){ int d = i/25, c = 207 + i%25; Vt[d*KVH + c] = (_Float16)0.0f; }
  for (int i = tid; i < 64*24; i += 256){ int row = i/24, c = 208 + i%24; Ps[row*KVH + c] = (_Float16)0.0f; }
  for (int i = tid; i < SLAB; i += 256){
    int n = i >> 4, d = i & 15;
    Vt[d*KVH + n] = (_Float16)b2f(Vslab[i]);
  }
  __syncthreads();

  int lane = tid & 63, w = tid >> 6, quad = lane >> 4, cl = lane & 15;
  f16x8 ones8;
  #pragma unroll
  for (int j = 0; j < 8; j++) ones8[j] = (_Float16)1.0f;
  int nstripes = (w == 0) ? 4 : 3;
  for (int si = 0; si < nstripes; si++){
    int mi = w + si*4;          // 0..12
    bf16x8 aq = (bf16x8){0,0,0,0,0,0,0,0};
    {
      int n = mi*16 + cl; if (n > N_-1) n = N_-1;   // clamp pad row (never stored)
      if (quad < 2) aq = *(const bf16x8*)(Qslab + n*16 + quad*8);
    }
    const float* mrow = maskg + ((size_t)mi*13)*256 + lane*4;
    f32x4 s[13];
    #pragma unroll
    for (int nj = 0; nj < 13; nj++){
      bf16x8 bk = (bf16x8){0,0,0,0,0,0,0,0};
      if (quad < 2){
        int nb = nj*16 + cl; if (nb > N_-1) nb = N_-1;  // clamped col masked by -1e30
        bk = *(const bf16x8*)(Kslab + nb*16 + quad*8);
      }
      f32x4 c0 = *(const f32x4*)(mrow + nj*256);
      s[nj] = __builtin_amdgcn_mfma_f32_16x16x32_bf16(aq, bk, c0, 0,0,0);
    }
    int row0 = mi*16 + quad*4;
    _Float16* Pw = Ps + w*16*KVH;
    #pragma unroll
    for (int r = 0; r < 4; r++){
      _Float16* Pr = Pw + (quad*4 + r)*KVH;
      #pragma unroll
      for (int nj = 0; nj < 13; nj++)
        Pr[nj*16 + cl] = (_Float16)exp2f(s[nj][r]);
    }
    __threadfence_block();   // order P writes before same-wave PV reads
    f32x4 o = {0.f,0.f,0.f,0.f};
    f32x4 osum = {0.f,0.f,0.f,0.f};
    #pragma unroll
    for (int kt = 0; kt < 7; kt++){
      f16x8 ap = *(const f16x8*)(Pw + cl*KVH + kt*32 + quad*8);
      f16x8 bv = *(const f16x8*)(Vt + cl*KVH + kt*32 + quad*8);
      o    = __builtin_amdgcn_mfma_f32_16x16x32_f16(ap, bv,    o,    0,0,0);
      osum = __builtin_amdgcn_mfma_f32_16x16x32_f16(ap, ones8, osum, 0,0,0);
    }
    #pragma unroll
    for (int r = 0; r < 4; r++){
      int rg = row0 + r;
      if (rg < N_)
        ob[((size_t)((b*N_ + rg)*T_ + t))*D_ + hh*HD_ + cl] = f2b(o[r]/osum[r]);
    }
    __threadfence_block();   // order PV reads before next stripe's P writes
  }
}

// ---- temporal attention ----
__global__ void tattn_k(const bf16* qkv, bf16* ob){
  int bid = blockIdx.x; int b = bid / N_, n = bid % N_;
  __shared__ float qs[T_*D_];
  __shared__ float ks[T_*D_];
  __shared__ float vs[T_*D_];
  size_t rowb = ((size_t)(b*N_+n)*T_)*384;
  const u32* src = (const u32*)(qkv + rowb);
  for (int idx = threadIdx.x; idx < T_*192; idx += 128){
    int tt = idx / 192, cw = idx - tt*192;
    u32 pr = src[tt*192 + cw];
    union { u32 u; bf16 b[2]; } cv; cv.u = pr;
    float v0 = b2f(cv.b[0]), v1 = b2f(cv.b[1]);
    int arr = cw >> 6, cp2 = (cw & 63)*2;
    float* dst = (arr == 0) ? qs : (arr == 1) ? ks : vs;
    dst[tt*128 + cp2] = v0; dst[tt*128 + cp2 + 1] = v1;
  }
  __syncthreads();
  int p = threadIdx.x;
  if (p < H_*T_){
    int hh = p / T_, t = p - hh*T_;
    float qreg[16];
    for (int d = 0; d < 16; d++) qreg[d] = qs[t*128 + hh*16 + d];
    float sc[12]; float mx = -3.4e38f;
    for (int s = 0; s < 12; s++){
      float a = 0.0f;
      for (int d = 0; d < 16; d++) a += qreg[d]*ks[s*128 + hh*16 + d];
      a = (s <= t) ? a*SCALE_ : -3.4e38f;
      sc[s] = a; mx = fmaxf(mx, a);
    }
    float ssum = 0.0f;
    for (int s = 0; s < 12; s++){
      float e = (s <= t) ? __expf(sc[s]-mx) : 0.0f;
      sc[s] = e; ssum += e;
    }
    float inv = 1.0f/ssum;
    size_t obase = ((size_t)(b*N_+n)*T_ + t)*D_ + hh*16;
    for (int d = 0; d < 16; d++){
      float acc = 0.0f;
      for (int s = 0; s < 12; s++) acc += sc[s]*vs[s*128 + hh*16 + d];
      ob[obase + d] = f2b(acc*inv);
    }
  }
}

// ---- VALU GEMM for small head GEMMs ----
__global__ void gemm_k(const bf16* A, int lda, const bf16* W, const bf16* bias,
                       void* outp, int ldo, int M, int Ncols, int K, int relu, int acc){
  __shared__ float Ast[16*68];
  __shared__ float Ws [16*68];
  int tx = threadIdx.x & 15, ty = threadIdx.x >> 4;
  int rowBase = blockIdx.y * 64, colBase = blockIdx.x * 64;
  float accr[4][4];
  for (int i = 0; i < 4; i++) for (int j = 0; j < 4; j++) accr[i][j] = 0.0f;
  for (int kk = 0; kk < K; kk += 16){
    int kq = threadIdx.x & 15, r0 = threadIdx.x >> 4;
    for (int it = 0; it < 4; it++){
      int r = r0 + it*16, row = rowBase + r;
      float v = 0.0f;
      if (row < M) v = b2f(A[(size_t)row*lda + kk + kq]);
      Ast[kq*68 + r] = v;
    }
    int c = threadIdx.x & 63, w0 = threadIdx.x >> 6;
    for (int it = 0; it < 4; it++){
      int kr = w0 + it*4;
      Ws[kr*68 + c] = b2f(W[(size_t)(kk+kr)*Ncols + colBase + c]);
    }
    __syncthreads();
    for (int k = 0; k < 16; k++){
      float av[4], wv[4];
      for (int i = 0; i < 4; i++) av[i] = Ast[k*68 + ty*4 + i];
      for (int j = 0; j < 4; j++) wv[j] = Ws[k*68 + tx*4 + j];
      for (int i = 0; i < 4; i++)
        for (int j = 0; j < 4; j++) accr[i][j] += av[i]*wv[j];
    }
    __syncthreads();
  }
  for (int i = 0; i < 4; i++){
    int row = rowBase + ty*4 + i;
    if (row >= M) continue;
    for (int j = 0; j < 4; j++){
      int col = colBase + tx*4 + j;
      float v = accr[i][j];
      if (bias) v += b2f(bias[col]);
      if (relu) v = fmaxf(v, 0.0f);
      if (acc) ((float*)outp)[(size_t)row*ldo + col] += v;
      else     ((bf16*)outp)[(size_t)row*ldo + col] = f2b(v);
    }
  }
}

__global__ void gather_k(const float* h, bf16* hlb){
  int i = blockIdx.x*256 + threadIdx.x;
  if (i >= ROWS2*D_) return;
  int r = i >> 7, d = i & 127;
  hlb[i] = f2b(h[((size_t)r*T_ + (T_-1))*D_ + d]);
}

__global__ void head3_k(const bf16* z2, const bf16* P3, const bf16* Pb3,
                        void* out, int out_n, const int* flag){
  int i = blockIdx.x*256 + threadIdx.x;
  if (i >= out_n) return;
  int r = i / PL_, j = i - r*PL_;
  float acc = b2f(Pb3[j]);
  for (int d = 0; d < 128; d++) acc += b2f(z2[(size_t)r*128 + d]) * b2f(P3[d*PL_ + j]);
  if (*flag) ((bf16*)out)[i] = f2b(acc);
  else       ((float*)out)[i] = acc;
}

extern "C" void kernel_launch(void* const* d_in, const int* in_sizes, int n_in,
                              void* d_out, int out_size, void* d_ws, size_t ws_size,
                              hipStream_t stream){
  size_t HB = (size_t)TOK*D_*4;
  size_t XB = (size_t)TOK*D_*2;
  size_t RB = (size_t)TOK*D_*8;
  float* h    = (float*)d_ws;
  bf16*  xnb  = (bf16*)((char*)d_ws + HB);
  bf16*  reg_ = (bf16*)((char*)d_ws + HB + XB);
  bf16*  cvt  = (bf16*)((char*)d_ws + HB + XB + RB);
  bf16*  wsb  = (bf16*)d_ws;
  const int FIDX[34] = {0,2,3,4,5,6,7,8,9,10,11,12,13,14,15,16,17,18,19,20,
                        21,22,23,24,25,26,27,28,29,30,31,32,33,34};
  bf16* cp[34];
  size_t off = 0;
  for (int i = 0; i < 34; i++){ cp[i] = cvt + off; off += (size_t)in_sizes[FIDX[i]]; }
  char* tail   = (char*)d_ws + HB + XB + RB + ((off*2 + 255) & ~(size_t)255);
  float* maskg = (float*)tail;
  bf16* qkvw   = (bf16*)(tail + (size_t)MSK_N*4);
  int*  flag   = (int*)(tail + (size_t)MSK_N*4 + (size_t)L_*384*128*2);

  const bf16 *x_c=cp[0], *Wi_c=cp[1], *bi_c=cp[2],
             *Wo_t=cp[6], *bo_c=cp[7], *sW1_t=cp[8], *sB1_c=cp[9], *sW2_t=cp[10], *sB2_c=cp[11],
             *sg1_c=cp[12], *sh1_c=cp[13], *sg2_c=cp[14], *sh2_c=cp[15], *Win_t=cp[16], *Bin_c=cp[17],
             *Wout_t=cp[18], *Bout_c=cp[19], *tW1_t=cp[20], *tB1_c=cp[21], *tW2_t=cp[22], *tB2_c=cp[23],
             *tg1_c=cp[24], *th1_c=cp[25], *tg2_c=cp[26], *th2_c=cp[27], *P1_c=cp[28], *Pb1_c=cp[29],
             *P2_c=cp[30], *Pb2_c=cp[31], *P3_c=cp[32], *Pb3_c=cp[33];
  const int* adj = (const int*)d_in[1];

  bf16* sQ   = reg_;
  bf16* sK   = reg_ + (size_t)TOK*128;
  bf16* sV   = reg_ + (size_t)2*TOK*128;
  bf16* ob   = reg_ + (size_t)3*TOK*128;
  bf16* qkvb = reg_;

  detect_k<<<1, 256, 0, stream>>>(d_in[0], flag);

  {
    const int FLAT[24] = {0,1,2,7,9,11,12,13,14,15,17,19,21,23,24,25,26,27,28,29,30,31,32,33};
    FlatArgs fa; int c = 0;
    for (int ii = 0; ii < 24; ii++){
      int ci = FLAT[ii];
      fa.src[ii] = d_in[FIDX[ci]];
      fa.dst[ii] = (long long)(cp[ci] - wsb);
      fa.cum[ii] = c;
      c += in_sizes[FIDX[ci]];
    }
    fa.cum[24] = c;
    cvt_flat_k<<<(c+255)/256, 256, 0, stream>>>(fa, wsb, flag, c);
  }
  {
    TArgs ta; int c = 0;
    const void* srcs[10] = {d_in[4], d_in[5], d_in[6], d_in[7], d_in[9], d_in[11],
                            d_in[17], d_in[19], d_in[21], d_in[23]};
    bf16* dsts[10] = {qkvw, qkvw, qkvw, cp[6], cp[8], cp[10], cp[16], cp[18], cp[20], cp[22]};
    int Ks_[10]   = {128,128,128, 128, 128, 512, 128, 128, 128, 512};
    int Ncs[10]   = {128,128,128, 128, 512, 128, 384, 128, 512, 128};
    int Lst[10]   = {384*128,384*128,384*128, 128*128, 128*512, 512*128, 128*384, 128*128, 128*512, 512*128};
    int ros[10]   = {0,128,256, 0,0,0, 0,0,0, 0};
    for (int j = 0; j < 10; j++){
      ta.src[j] = srcs[j];
      ta.dst[j] = (long long)(dsts[j] - wsb);
      ta.K[j] = Ks_[j]; ta.Nc[j] = Ncs[j]; ta.Lstr[j] = Lst[j]; ta.ro[j] = ros[j];
      ta.scale[j] = (j == 0) ? SCALE_*LOG2E_ : 1.0f;   // fold softmax log2e into Wq
      ta.cum[j] = c;
      c += L_*Ks_[j]*Ncs[j];
    }
    ta.cum[10] = c;
    cvt_t_k<<<(c+255)/256, 256, 0, stream>>>(ta, wsb, flag, c);
  }
  maskc_k<<<(MSK_N+255)/256, 256, 0, stream>>>(adj, maskg);
  embed_ln_k<<<TOK/4, 256, 0, stream>>>(x_c, Wi_c, bi_c, sg1_c, sh1_c, h, xnb);

  const dim3 gP  (1, TOK/128);
  const dim3 gQKV(3, TOK/128);

  for (int l = 0; l < L_; l++){
    // spatial attention
    mgemm_qkvT_k<<<gQKV, 256, 0, stream>>>(xnb, qkvw + (size_t)l*384*128, sQ, sK, sV);
    sattn_k<<<B_*T_*H_, 256, 0, stream>>>(sQ, sK, sV, maskg, ob);
    mgemm_ln_k<<<gP, 256, 0, stream>>>(ob, Wo_t + (size_t)l*D_*D_, bo_c + l*D_, h, D_,
                                       sg2_c + l*D_, sh2_c + l*D_, xnb);
    // fused FFN 1 (-> LN tg1)
    mffn_ln_k<<<TOK/128, 256, 0, stream>>>(xnb, sW1_t + (size_t)l*D_*FF_, sB1_c + l*FF_,
                                           sW2_t + (size_t)l*FF_*D_, sB2_c + l*D_, h,
                                           tg1_c + l*D_, th1_c + l*D_, xnb);
    // temporal attention
    mgemm_k<<<gQKV, 256, 0, stream>>>(xnb, Win_t + (size_t)l*D_*384, Bin_c + l*384, qkvb, 384, D_, 0);
    tattn_k<<<B_*N_, 128, 0, stream>>>(qkvb, ob);
    mgemm_ln_k<<<gP, 256, 0, stream>>>(ob, Wout_t + (size_t)l*D_*D_, Bout_c + l*D_, h, D_,
                                       tg2_c + l*D_, th2_c + l*D_, xnb);
    // fused FFN 2 (-> LN next sg1 or none)
    const bf16* gnext = (l < L_-1) ? (sg1_c + (l+1)*D_) : nullptr;
    const bf16* bnext = (l < L_-1) ? (sh1_c + (l+1)*D_) : nullptr;
    mffn_ln_k<<<TOK/128, 256, 0, stream>>>(xnb, tW1_t + (size_t)l*D_*FF_, tB1_c + l*FF_,
                                           tW2_t + (size_t)l*FF_*D_, tB2_c + l*D_, h,
                                           gnext, bnext, xnb);
  }

  // head
  bf16* hlb = reg_;
  bf16* z1  = reg_ + (size_t)ROWS2*128;
  bf16* z2  = z1   + (size_t)ROWS2*256;
  gather_k<<<(ROWS2*D_)/256, 256, 0, stream>>>(h, hlb);
  gemm_k<<<dim3(256/64, (ROWS2+63)/64), 256, 0, stream>>>(hlb, 128, P1_c, Pb1_c, z1, 256, ROWS2, 256, 128, 1, 0);
  gemm_k<<<dim3(128/64, (ROWS2+63)/64), 256, 0, stream>>>(z1, 256, P2_c, Pb2_c, z2, 128, ROWS2, 128, 256, 1, 0);
  head3_k<<<(out_size+255)/256, 256, 0, stream>>>(z2, P3_c, Pb3_c, d_out, out_size, flag);
}